// Round 9
// baseline (948.374 us; speedup 1.0000x reference)
//
#include <hip/hip_runtime.h>
#include <hip/hip_bf16.h>

// SACRSN_v84 — v9: fused_main occupancy fix.
//   - __launch_bounds__(256,4): VGPR<=128 -> 4 blocks/CU (whole grid resident).
//   - P1 VQ argmin: single-pass parallel reduce (2 barriers instead of 24).
//   mem_kernel / finalize unchanged from passing R8.

#define NROWS 8
#define NBLOCKS 1024
#define RSTRIDE 4736

static constexpr size_t OFF_VQLOSS = 38797312UL;  // 8192*4736
static constexpr size_t OFF_IDX    = 38805504UL;
static constexpr size_t OFF_SENT   = 38813696UL;
static constexpr size_t OFF_NENT   = 38813697UL;

struct Params {
  const float* curr_r; const float* curr_i;
  const float* mem_r;  const float* mem_i;
  const float* codebook;
  const float* qkv_Wr; const float* qkv_Wi; const float* qkv_br; const float* qkv_bi;
  const float* quad_Wr; const float* quad_Wi; const float* quad_br; const float* quad_bi;
  const float* sens_Wr; const float* sens_Wi; const float* sens_br; const float* sens_bi;
  const float* vis_pal; const float* aud_pal;
  const float* gate_W; const float* gate_b;
  const float* addr_W; const float* addr_b;
  const float* ln_gr; const float* ln_br; const float* ln_gi; const float* ln_bi;
  float* out;
  int* hist;          // ws: 128 ints
  float* rowent;      // ws + 512 B: 8192 floats
};

union __align__(16) ScratchU {
  struct { double cbn[128]; double dall[NROWS][256]; } vq;        // 17.4 KB
  float w[64][64];                                                // 16 KB staged weights
  struct { float vis[NROWS][128]; float palp[NROWS][32]; } pal;   // 5 KB
};

// ================= kernel A: per-row dense math (no mem_r/mem_i) =================
__global__ __launch_bounds__(256, 4) void fused_main(Params P) {
  const int t = threadIdx.x;
  const int bid = blockIdx.x;
  const int lane = t & 63;
  const int wv = t >> 6;

  __shared__ __align__(16) float s_zr[NROWS][64], s_zi[NROWS][64];
  __shared__ ScratchU u;
  __shared__ float s_qr[NROWS][64], s_qi[NROWS][64];
  __shared__ float s_kr[NROWS][64], s_ki[NROWS][64];
  __shared__ float s_vr[NROWS][64], s_vi[NROWS][64];
  __shared__ __align__(16) float s_sf[NROWS][128];
  __shared__ float s_gate[NROWS], s_vqls[NROWS];
  __shared__ int s_idx[NROWS];

  // ---- P0: stage curr (z) ----
  {
    const float* cr = P.curr_r + (size_t)bid * (NROWS * 64);
    const float* ci = P.curr_i + (size_t)bid * (NROWS * 64);
    float* zr = &s_zr[0][0];
    float* zi = &s_zi[0][0];
    for (int i = t; i < NROWS * 64; i += 256) { zr[i] = cr[i]; zi[i] = ci[i]; }
  }

  // ---- P0b: codebook squared norms (f64), partials in u.vq.dall[0] ----
  {
    const float* cb = P.codebook + (t & 127) * 128 + (t >> 7) * 64;
    double a = 0.0;
    for (int d = 0; d < 64; ++d) { double w = (double)cb[d]; a = fma(w, w, a); }
    u.vq.dall[0][t] = a;
    __syncthreads();                       // also publishes s_zr/s_zi
    if (t < 128) u.vq.cbn[t] = u.vq.dall[0][t] + u.vq.dall[0][t + 128];
    __syncthreads();
  }

  // ---- P1: VQ argmin — all rows parallel, 2 barriers ----
  {
    const int c = t & 127, h = t >> 7;
    const float* cb = P.codebook + c * 128 + h * 64;
    const float (*zb)[64] = h ? s_zi : s_zr;
    double acc[NROWS];
    #pragma unroll
    for (int r = 0; r < NROWS; ++r) acc[r] = 0.0;
    for (int d = 0; d < 64; ++d) {
      const double w = (double)cb[d];
      #pragma unroll
      for (int r = 0; r < NROWS; ++r) acc[r] = fma(w, (double)zb[r][d], acc[r]);
    }
    #pragma unroll
    for (int r = 0; r < NROWS; ++r) u.vq.dall[r][h * 128 + c] = acc[r];
    __syncthreads();
    // wave wv reduces rows 2wv, 2wv+1; lane l covers codes l and l+64
    #pragma unroll
    for (int rr = 0; rr < 2; ++rr) {
      const int r = wv * 2 + rr;
      const double d0 = u.vq.cbn[lane]      - 2.0 * (u.vq.dall[r][lane]      + u.vq.dall[r][128 + lane]);
      const double d1 = u.vq.cbn[lane + 64] - 2.0 * (u.vq.dall[r][64 + lane] + u.vq.dall[r][192 + lane]);
      double sv = d0; int si = lane;
      if (d1 < sv) { sv = d1; si = lane + 64; }   // tie keeps lower idx
      #pragma unroll
      for (int m = 1; m <= 32; m <<= 1) {
        double ov = __shfl_xor(sv, m);
        int oi = __shfl_xor(si, m);
        if (ov < sv || (ov == sv && oi < si)) { sv = ov; si = oi; }
      }
      if (lane == 0) { s_idx[r] = si; atomicAdd(&P.hist[si], 1); }
    }
    __syncthreads();
  }

  // ---- P1b: vq_loss ----
  {
    #pragma unroll
    for (int rr = 0; rr < 2; ++rr) {
      const int r = wv * 2 + rr;
      const float* cb = P.codebook + (size_t)s_idx[r] * 128;
      float d0_ = cb[lane] - s_zr[r][lane];
      float d1_ = cb[64 + lane] - s_zi[r][lane];
      float v = d0_ * d0_ + d1_ * d1_;
      #pragma unroll
      for (int m = 1; m <= 32; m <<= 1) v += __shfl_xor(v, m);
      if (lane == 0) s_vqls[r] = 0.25f * v * (1.0f / 128.0f);
    }
  }

  // ---- P2: five complex linears ----
  {
    const int j = t & 63, rg = t >> 6;
    const float* Wr_tab[5] = {P.qkv_Wr, P.qkv_Wr + 4096, P.qkv_Wr + 8192, P.quad_Wr, P.sens_Wr};
    const float* Wi_tab[5] = {P.qkv_Wi, P.qkv_Wi + 4096, P.qkv_Wi + 8192, P.quad_Wi, P.sens_Wi};
    const float* br_tab[5] = {P.qkv_br, P.qkv_br + 64, P.qkv_br + 128, P.quad_br, P.sens_br};
    const float* bi_tab[5] = {P.qkv_bi, P.qkv_bi + 64, P.qkv_bi + 128, P.quad_bi, P.sens_bi};
    #pragma unroll 1
    for (int cl = 0; cl < 5; ++cl) {
      __syncthreads();
      { const float4* src = (const float4*)Wr_tab[cl];
        float4* dst = (float4*)&u.w[0][0];
        for (int i = t; i < 1024; i += 256) dst[i] = src[i]; }
      __syncthreads();
      float aRR0 = 0.f, aRR1 = 0.f, aIR0 = 0.f, aIR1 = 0.f;
      for (int d4 = 0; d4 < 64; d4 += 4) {
        float4 zr0 = *(const float4*)&s_zr[rg][d4];
        float4 zr1 = *(const float4*)&s_zr[rg + 4][d4];
        float4 zi0 = *(const float4*)&s_zi[rg][d4];
        float4 zi1 = *(const float4*)&s_zi[rg + 4][d4];
        float w0 = u.w[d4 + 0][j], w1 = u.w[d4 + 1][j];
        float w2 = u.w[d4 + 2][j], w3 = u.w[d4 + 3][j];
        aRR0 += zr0.x * w0 + zr0.y * w1 + zr0.z * w2 + zr0.w * w3;
        aRR1 += zr1.x * w0 + zr1.y * w1 + zr1.z * w2 + zr1.w * w3;
        aIR0 += zi0.x * w0 + zi0.y * w1 + zi0.z * w2 + zi0.w * w3;
        aIR1 += zi1.x * w0 + zi1.y * w1 + zi1.z * w2 + zi1.w * w3;
      }
      __syncthreads();
      { const float4* src = (const float4*)Wi_tab[cl];
        float4* dst = (float4*)&u.w[0][0];
        for (int i = t; i < 1024; i += 256) dst[i] = src[i]; }
      __syncthreads();
      float aRI0 = 0.f, aRI1 = 0.f, aII0 = 0.f, aII1 = 0.f;
      for (int d4 = 0; d4 < 64; d4 += 4) {
        float4 zr0 = *(const float4*)&s_zr[rg][d4];
        float4 zr1 = *(const float4*)&s_zr[rg + 4][d4];
        float4 zi0 = *(const float4*)&s_zi[rg][d4];
        float4 zi1 = *(const float4*)&s_zi[rg + 4][d4];
        float w0 = u.w[d4 + 0][j], w1 = u.w[d4 + 1][j];
        float w2 = u.w[d4 + 2][j], w3 = u.w[d4 + 3][j];
        aRI0 += zr0.x * w0 + zr0.y * w1 + zr0.z * w2 + zr0.w * w3;
        aRI1 += zr1.x * w0 + zr1.y * w1 + zr1.z * w2 + zr1.w * w3;
        aII0 += zi0.x * w0 + zi0.y * w1 + zi0.z * w2 + zi0.w * w3;
        aII1 += zi1.x * w0 + zi1.y * w1 + zi1.z * w2 + zi1.w * w3;
      }
      const float brj = br_tab[cl][j], bij = bi_tab[cl][j];
      #pragma unroll
      for (int hh = 0; hh < 2; ++hh) {
        const int r = rg + hh * 4;
        const float pRR = hh ? aRR1 : aRR0;
        const float pII = hh ? aII1 : aII0;
        const float pRI = hh ? aRI1 : aRI0;
        const float pIR = hh ? aIR1 : aIR0;
        const float oR = (pRR + brj) - (pII + bij);
        const float oI = (pRI + bij) + (pIR + brj);
        if (cl == 0)      { s_qr[r][j] = oR; s_qi[r][j] = oI; }
        else if (cl == 1) { s_kr[r][j] = oR; s_ki[r][j] = oI; }
        else if (cl == 2) { s_vr[r][j] = oR; s_vi[r][j] = oI; }
        else if (cl == 3) {
          float* orow = P.out + ((size_t)bid * NROWS + r) * RSTRIDE;
          orow[512 + j] = -oI;
          orow[576 + j] = oR;
        } else            { s_sf[r][j] = oR; s_sf[r][64 + j] = oI; }
      }
    }
    __syncthreads();
  }

  // ---- P3: gate only ----
  {
    const int r = t >> 5, l = t & 31;
    float g = s_qr[r][l] * s_kr[r][l] + s_qi[r][l] * s_ki[r][l]
            + s_qr[r][l + 32] * s_kr[r][l + 32] + s_qi[r][l + 32] * s_ki[r][l + 32];
    #pragma unroll
    for (int m = 16; m >= 1; m >>= 1) g += __shfl_xor(g, m);
    if (l == 0) s_gate[r] = 1.f / (1.f + expf(-g));
  }
  __syncthreads();

  // ---- P5: palette attends ----
  {
    const int r = t >> 5, a = t & 31;
    float sc = 0.f;
    for (int jj = 0; jj < 128; jj += 4) {
      const float4 sf = *(const float4*)&s_sf[r][jj];
      const float4 pv = *(const float4*)&P.vis_pal[a * 128 + jj];
      sc += sf.x * pv.x + sf.y * pv.y + sf.z * pv.z + sf.w * pv.w;
    }
    float mx = sc;
    #pragma unroll
    for (int m = 16; m >= 1; m >>= 1) mx = fmaxf(mx, __shfl_xor(mx, m));
    float e = expf(sc - mx);
    float sm = e;
    #pragma unroll
    for (int m = 16; m >= 1; m >>= 1) sm += __shfl_xor(sm, m);
    u.pal.palp[r][a] = e / sm;
  }
  __syncthreads();
  {
    const int j = t & 127, rp = t >> 7;
    float acc[4] = {0.f, 0.f, 0.f, 0.f};
    for (int a = 0; a < 32; ++a) {
      const float pv = P.vis_pal[a * 128 + j];
      #pragma unroll
      for (int q = 0; q < 4; ++q) acc[q] += u.pal.palp[rp + q * 2][a] * pv;
    }
    #pragma unroll
    for (int q = 0; q < 4; ++q) u.pal.vis[rp + q * 2][j] = acc[q];
  }
  __syncthreads();
  {
    const int r = t >> 5, a = t & 31;
    float sc = 0.f;
    for (int jj = 0; jj < 128; jj += 4) {
      const float4 sf = *(const float4*)&s_sf[r][jj];
      const float4 pv = *(const float4*)&P.aud_pal[a * 128 + jj];
      sc += sf.x * pv.x + sf.y * pv.y + sf.z * pv.z + sf.w * pv.w;
    }
    float mx = sc;
    #pragma unroll
    for (int m = 16; m >= 1; m >>= 1) mx = fmaxf(mx, __shfl_xor(mx, m));
    float e = expf(sc - mx);
    float sm = e;
    #pragma unroll
    for (int m = 16; m >= 1; m >>= 1) sm += __shfl_xor(sm, m);
    u.pal.palp[r][a] = e / sm;
  }
  __syncthreads();
  {
    const int j = t & 127, rp = t >> 7;
    float acc[4] = {0.f, 0.f, 0.f, 0.f};
    for (int a = 0; a < 32; ++a) {
      const float pv = P.aud_pal[a * 128 + j];
      #pragma unroll
      for (int q = 0; q < 4; ++q) acc[q] += u.pal.palp[rp + q * 2][a] * pv;
    }
    #pragma unroll
    for (int q = 0; q < 4; ++q) {
      const int rr = rp + q * 2;
      const size_t bb = (size_t)bid * NROWS + rr;
      float* orow = P.out + bb * RSTRIDE;
      if (j < 64) orow[448 + j] = u.pal.vis[rr][64 + j] + acc[q];        // exp_i
      else        orow[384 + (j - 64)] = u.pal.vis[rr][j - 64] - acc[q]; // exp_r
    }
  }

  // ---- P6: vq_r/vq_i, g_r/g_i, scalars ----
  {
    const int j = t & 63, g = t >> 6;
    #pragma unroll 1
    for (int r = 0; r < NROWS; ++r) {
      const size_t bb = (size_t)bid * NROWS + r;
      float* orow = P.out + bb * RSTRIDE;
      if (g == 0) {
        float z = s_zr[r][j];
        float cv = P.codebook[(size_t)s_idx[r] * 128 + j];
        orow[j] = z + (cv - z);
      } else if (g == 1) {
        float z = s_zi[r][j];
        float cv = P.codebook[(size_t)s_idx[r] * 128 + 64 + j];
        orow[64 + j] = z + (cv - z);
      } else if (g == 2) {
        orow[128 + j] = s_vr[r][j] * s_gate[r];
      } else {
        orow[192 + j] = s_vi[r][j] * s_gate[r];
      }
    }
  }
  if (t < NROWS) {
    P.out[OFF_VQLOSS + (size_t)bid * NROWS + t] = s_vqls[t];
    P.out[OFF_IDX + (size_t)bid * NROWS + t] = (float)s_idx[t];
  }
}

// ================= kernel B: per-row memory attention + tanh/LN (streaming) =================
__global__ __launch_bounds__(256, 4) void mem_kernel(Params P) {
  const int b = blockIdx.x;       // row 0..8191
  const int t = threadIdx.x;
  const int lane = t & 63;
  const int wv = t >> 6;

  __shared__ float zr[64], zi[64];
  __shared__ float lp[4][32];
  __shared__ float s_eff[32];
  __shared__ float s_sim[32], s_attn[32];
  __shared__ float s_rr[4][8][8], s_ri[4][8][8];
  __shared__ float s_wg;

  // phase 1: stage z
  if (t < 64)       zr[t]      = P.curr_r[(size_t)b * 64 + t];
  else if (t < 128) zi[t - 64] = P.curr_i[(size_t)b * 64 + (t - 64)];
  __syncthreads();

  // phase 2: mem loads + sim partials; addr-logit partials; write_gate partial
  const size_t bb = (size_t)b;
  const int s = t >> 3, k = t & 7, d0 = k * 8;
  const float* mrp = P.mem_r + ((bb * 32 + s) * 64 + d0);
  const float* mip = P.mem_i + ((bb * 32 + s) * 64 + d0);
  float4 a0 = *(const float4*)mrp, a1 = *(const float4*)(mrp + 4);
  float4 b0 = *(const float4*)mip, b1 = *(const float4*)(mip + 4);
  float mr[8] = {a0.x, a0.y, a0.z, a0.w, a1.x, a1.y, a1.z, a1.w};
  float mi[8] = {b0.x, b0.y, b0.z, b0.w, b1.x, b1.y, b1.z, b1.w};

  if (t < 128) {
    const int q = t >> 5, l = t & 31;
    const float* zz = (q < 2) ? zr : zi;
    const int zb = (q & 1) * 32;
    float a = 0.f;
    for (int i = 0; i < 32; ++i) a += zz[zb + i] * P.addr_W[(q * 32 + i) * 32 + l];
    lp[q][l] = a;
  } else if (t < 192) {
    const int j = t - 128;          // 0..63, wave 2
    float tw = zr[j] * P.gate_W[j] + zi[j] * P.gate_W[64 + j];
    #pragma unroll
    for (int m = 1; m <= 32; m <<= 1) tw += __shfl_xor(tw, m);
    if (j == 0) s_wg = tw;
  }

  float sp = 0.f;
  #pragma unroll
  for (int x = 0; x < 8; ++x) sp += mr[x] * zr[d0 + x] + mi[x] * zi[d0 + x];
  sp += __shfl_xor(sp, 1); sp += __shfl_xor(sp, 2); sp += __shfl_xor(sp, 4);
  if (k == 0) s_sim[s] = sp;
  __syncthreads();

  // phase 3: wave 0 -> sim softmax; wave 1 lanes 0..31 -> addr softmax/top3/eff
  if (t < 32) {
    float v = s_sim[t];
    float mx = v;
    #pragma unroll
    for (int m = 16; m >= 1; m >>= 1) mx = fmaxf(mx, __shfl_xor(mx, m));
    float e = expf(v - mx);
    float sm = e;
    #pragma unroll
    for (int m = 16; m >= 1; m >>= 1) sm += __shfl_xor(sm, m);
    s_attn[t] = e / sm;
  } else if (t >= 64 && t < 96) {
    const int l = t - 64;
    float lg = lp[0][l] + lp[1][l] + lp[2][l] + lp[3][l] + P.addr_b[l];
    float mx = lg;
    #pragma unroll
    for (int m = 16; m >= 1; m >>= 1) mx = fmaxf(mx, __shfl_xor(mx, m));
    float e = expf(lg - mx);
    float sm = e;
    #pragma unroll
    for (int m = 16; m >= 1; m >>= 1) sm += __shfl_xor(sm, m);
    const float w = e / sm;
    float es = -(w * logf(w + 1e-10f));
    #pragma unroll
    for (int m = 16; m >= 1; m >>= 1) es += __shfl_xor(es, m);
    if (l == 0) P.rowent[b] = es;
    // top-3 (lax.top_k: ties -> lower index)
    const float myw = w;
    bool picked = false;
    float val = w; int idx = l;
    float sumtop = 0.f;
    #pragma unroll
    for (int it = 0; it < 3; ++it) {
      float v2 = val; int i2 = idx;
      #pragma unroll
      for (int m = 16; m >= 1; m >>= 1) {
        float ov = __shfl_xor(v2, m); int oi = __shfl_xor(i2, m);
        if (ov > v2 || (ov == v2 && oi < i2)) { v2 = ov; i2 = oi; }
      }
      sumtop += v2;
      if (l == i2) { picked = true; val = -1e30f; }
    }
    const float wgate = 1.f / (1.f + expf(-(s_wg + P.gate_b[0])));
    s_eff[l] = picked ? wgate * (myw / (sumtop + 1e-6f)) : 0.f;
  }
  __syncthreads();

  // phase 4: read reduction + tanh/LN + stores
  const float aw = s_attn[s];
  {
    float pr[8], pi[8];
    #pragma unroll
    for (int x = 0; x < 8; ++x) { pr[x] = aw * mr[x]; pi[x] = aw * mi[x]; }
    #pragma unroll
    for (int m = 8; m <= 32; m <<= 1) {
      #pragma unroll
      for (int x = 0; x < 8; ++x) { pr[x] += __shfl_xor(pr[x], m); pi[x] += __shfl_xor(pi[x], m); }
    }
    if (lane < 8) {
      #pragma unroll
      for (int x = 0; x < 8; ++x) { s_rr[wv][lane][x] = pr[x]; s_ri[wv][lane][x] = pi[x]; }
    }
  }
  // nm = layernorm(tanh(mem + eff*(curr - mem)))
  {
    const float eff = s_eff[s];
    float nr[8], ni[8];
    #pragma unroll
    for (int x = 0; x < 8; ++x) {
      nr[x] = tanhf(mr[x] + eff * (zr[d0 + x] - mr[x]));
      ni[x] = tanhf(mi[x] + eff * (zi[d0 + x] - mi[x]));
    }
    float sR = 0.f, sI = 0.f;
    #pragma unroll
    for (int x = 0; x < 8; ++x) { sR += nr[x]; sI += ni[x]; }
    sR += __shfl_xor(sR, 1); sR += __shfl_xor(sR, 2); sR += __shfl_xor(sR, 4);
    sI += __shfl_xor(sI, 1); sI += __shfl_xor(sI, 2); sI += __shfl_xor(sI, 4);
    const float mR = sR * (1.f / 64.f), mI = sI * (1.f / 64.f);
    float vR = 0.f, vI = 0.f;
    #pragma unroll
    for (int x = 0; x < 8; ++x) {
      float dr = nr[x] - mR; vR += dr * dr;
      float di = ni[x] - mI; vI += di * di;
    }
    vR += __shfl_xor(vR, 1); vR += __shfl_xor(vR, 2); vR += __shfl_xor(vR, 4);
    vI += __shfl_xor(vI, 1); vI += __shfl_xor(vI, 2); vI += __shfl_xor(vI, 4);
    const float invR = 1.f / sqrtf(vR * (1.f / 64.f) + 1e-6f);
    const float invI = 1.f / sqrtf(vI * (1.f / 64.f) + 1e-6f);
    float* orow = P.out + bb * RSTRIDE;
    float oR[8], oI[8];
    #pragma unroll
    for (int x = 0; x < 8; ++x) {
      const int d = d0 + x;
      oR[x] = (nr[x] - mR) * invR * P.ln_gr[d] + P.ln_br[d];
      oI[x] = (ni[x] - mI) * invI * P.ln_gi[d] + P.ln_bi[d];
    }
    *(float4*)&orow[640 + s * 64 + d0]      = make_float4(oR[0], oR[1], oR[2], oR[3]);
    *(float4*)&orow[640 + s * 64 + d0 + 4]  = make_float4(oR[4], oR[5], oR[6], oR[7]);
    *(float4*)&orow[2688 + s * 64 + d0]     = make_float4(oI[0], oI[1], oI[2], oI[3]);
    *(float4*)&orow[2688 + s * 64 + d0 + 4] = make_float4(oI[4], oI[5], oI[6], oI[7]);
  }
  __syncthreads();
  if (t < 64) {
    const int kk = t >> 3, xx = t & 7;
    float rv = s_rr[0][kk][xx] + s_rr[1][kk][xx] + s_rr[2][kk][xx] + s_rr[3][kk][xx];
    float iv = s_ri[0][kk][xx] + s_ri[1][kk][xx] + s_ri[2][kk][xx] + s_ri[3][kk][xx];
    float* orow = P.out + bb * RSTRIDE;
    orow[256 + t] = rv;
    orow[320 + t] = iv;
  }
}

__global__ __launch_bounds__(256) void finalize_k(const int* hist, const float* rowent,
                                                  float* out) {
  const int t = threadIdx.x;
  __shared__ float red[256];
  float se = 0.f;
  for (int i = t; i < 8192; i += 256) se += rowent[i];
  red[t] = se;
  __syncthreads();
  for (int off = 128; off >= 1; off >>= 1) {
    if (t < off) red[t] += red[t + off];
    __syncthreads();
  }
  if (t == 0) out[OFF_SENT] = red[0] / 8192.0f;
  __syncthreads();
  float ne = 0.f;
  if (t < 128) {
    const float pp = (float)hist[t] / 8192.0f;
    ne = -(pp * logf(pp + 1e-10f));
  }
  red[t] = ne;
  __syncthreads();
  for (int off = 128; off >= 1; off >>= 1) {
    if (t < off) red[t] += red[t + off];
    __syncthreads();
  }
  if (t == 0) out[OFF_NENT] = red[0] / logf(128.0f);
}

extern "C" void kernel_launch(void* const* d_in, const int* in_sizes, int n_in,
                              void* d_out, int out_size, void* d_ws, size_t ws_size,
                              hipStream_t stream) {
  (void)in_sizes; (void)n_in; (void)out_size; (void)ws_size;
  Params P;
  P.curr_r   = (const float*)d_in[0];
  P.curr_i   = (const float*)d_in[1];
  P.mem_r    = (const float*)d_in[2];
  P.mem_i    = (const float*)d_in[3];
  P.codebook = (const float*)d_in[4];
  P.qkv_Wr   = (const float*)d_in[5];
  P.qkv_Wi   = (const float*)d_in[6];
  P.qkv_br   = (const float*)d_in[7];
  P.qkv_bi   = (const float*)d_in[8];
  P.quad_Wr  = (const float*)d_in[9];
  P.quad_Wi  = (const float*)d_in[10];
  P.quad_br  = (const float*)d_in[11];
  P.quad_bi  = (const float*)d_in[12];
  P.sens_Wr  = (const float*)d_in[13];
  P.sens_Wi  = (const float*)d_in[14];
  P.sens_br  = (const float*)d_in[15];
  P.sens_bi  = (const float*)d_in[16];
  P.vis_pal  = (const float*)d_in[17];
  P.aud_pal  = (const float*)d_in[18];
  P.gate_W   = (const float*)d_in[19];
  P.gate_b   = (const float*)d_in[20];
  P.addr_W   = (const float*)d_in[21];
  P.addr_b   = (const float*)d_in[22];
  P.ln_gr    = (const float*)d_in[23];
  P.ln_br    = (const float*)d_in[24];
  P.ln_gi    = (const float*)d_in[25];
  P.ln_bi    = (const float*)d_in[26];
  P.out = (float*)d_out;
  P.hist = (int*)d_ws;
  P.rowent = (float*)((char*)d_ws + 512);

  hipMemsetAsync(d_ws, 0, 512, stream);
  mem_kernel<<<dim3(8192), dim3(256), 0, stream>>>(P);
  fused_main<<<dim3(NBLOCKS), dim3(256), 0, stream>>>(P);
  finalize_k<<<dim3(1), dim3(256), 0, stream>>>(P.hist, P.rowent, (float*)d_out);
}

// Round 10
// 946.144 us; speedup vs baseline: 1.0024x; 1.0024x over previous
//
#include <hip/hip_runtime.h>
#include <hip/hip_bf16.h>

// SACRSN_v84 — v10: phase-split slim kernels (R8 code verbatim per phase).
//   mem_kernel (8192 blk)  : mem attention + tanh/LN (R8 verified, unchanged)
//   vq_kernel  (1024 blk)  : VQ argmin (R9-verified parallel reduce) + vq writes
//   lin_kernel (1024 blk)  : complex linears + gate + palettes + g/exp/q writes
//   finalize_k             : scalars

#define NROWS 8
#define NBLOCKS 1024
#define RSTRIDE 4736

static constexpr size_t OFF_VQLOSS = 38797312UL;  // 8192*4736
static constexpr size_t OFF_IDX    = 38805504UL;
static constexpr size_t OFF_SENT   = 38813696UL;
static constexpr size_t OFF_NENT   = 38813697UL;

struct Params {
  const float* curr_r; const float* curr_i;
  const float* mem_r;  const float* mem_i;
  const float* codebook;
  const float* qkv_Wr; const float* qkv_Wi; const float* qkv_br; const float* qkv_bi;
  const float* quad_Wr; const float* quad_Wi; const float* quad_br; const float* quad_bi;
  const float* sens_Wr; const float* sens_Wi; const float* sens_br; const float* sens_bi;
  const float* vis_pal; const float* aud_pal;
  const float* gate_W; const float* gate_b;
  const float* addr_W; const float* addr_b;
  const float* ln_gr; const float* ln_br; const float* ln_gi; const float* ln_bi;
  float* out;
  int* hist;          // ws: 128 ints
  float* rowent;      // ws + 512 B: 8192 floats
};

// ================= vq_kernel: VQ argmin + vq/indices/vq_loss =================
__global__ void vq_kernel(Params P) {
  const int t = threadIdx.x;
  const int bid = blockIdx.x;
  const int lane = t & 63;
  const int wv = t >> 6;

  __shared__ __align__(16) float s_zr[NROWS][64], s_zi[NROWS][64];
  __shared__ double s_cbn[128];
  __shared__ double s_dall[NROWS][256];
  __shared__ float s_vqls[NROWS];
  __shared__ int s_idx[NROWS];

  // P0: stage z
  {
    const float* cr = P.curr_r + (size_t)bid * (NROWS * 64);
    const float* ci = P.curr_i + (size_t)bid * (NROWS * 64);
    float* zr = &s_zr[0][0];
    float* zi = &s_zi[0][0];
    for (int i = t; i < NROWS * 64; i += 256) { zr[i] = cr[i]; zi[i] = ci[i]; }
  }

  // P0b: codebook squared norms (f64)
  {
    const float* cb = P.codebook + (t & 127) * 128 + (t >> 7) * 64;
    double a = 0.0;
    for (int d = 0; d < 64; ++d) { double w = (double)cb[d]; a = fma(w, w, a); }
    s_dall[0][t] = a;
    __syncthreads();
    if (t < 128) s_cbn[t] = s_dall[0][t] + s_dall[0][t + 128];
    __syncthreads();
  }

  // P1: VQ argmin — all rows parallel (verified R9)
  {
    const int c = t & 127, h = t >> 7;
    const float* cb = P.codebook + c * 128 + h * 64;
    const float (*zb)[64] = h ? s_zi : s_zr;
    double acc[NROWS];
    #pragma unroll
    for (int r = 0; r < NROWS; ++r) acc[r] = 0.0;
    for (int d = 0; d < 64; ++d) {
      const double w = (double)cb[d];
      #pragma unroll
      for (int r = 0; r < NROWS; ++r) acc[r] = fma(w, (double)zb[r][d], acc[r]);
    }
    #pragma unroll
    for (int r = 0; r < NROWS; ++r) s_dall[r][h * 128 + c] = acc[r];
    __syncthreads();
    #pragma unroll
    for (int rr = 0; rr < 2; ++rr) {
      const int r = wv * 2 + rr;
      const double d0 = s_cbn[lane]      - 2.0 * (s_dall[r][lane]      + s_dall[r][128 + lane]);
      const double d1 = s_cbn[lane + 64] - 2.0 * (s_dall[r][64 + lane] + s_dall[r][192 + lane]);
      double sv = d0; int si = lane;
      if (d1 < sv) { sv = d1; si = lane + 64; }
      #pragma unroll
      for (int m = 1; m <= 32; m <<= 1) {
        double ov = __shfl_xor(sv, m);
        int oi = __shfl_xor(si, m);
        if (ov < sv || (ov == sv && oi < si)) { sv = ov; si = oi; }
      }
      if (lane == 0) { s_idx[r] = si; atomicAdd(&P.hist[si], 1); }
    }
    __syncthreads();
  }

  // P1b: vq_loss (verified)
  {
    #pragma unroll
    for (int rr = 0; rr < 2; ++rr) {
      const int r = wv * 2 + rr;
      const float* cb = P.codebook + (size_t)s_idx[r] * 128;
      float d0_ = cb[lane] - s_zr[r][lane];
      float d1_ = cb[64 + lane] - s_zi[r][lane];
      float v = d0_ * d0_ + d1_ * d1_;
      #pragma unroll
      for (int m = 1; m <= 32; m <<= 1) v += __shfl_xor(v, m);
      if (lane == 0) s_vqls[r] = 0.25f * v * (1.0f / 128.0f);
    }
  }
  __syncthreads();

  // vq_r/vq_i straight-through writes: group g: (g&1) r/i, (g>>1) row-half
  {
    const int j = t & 63, g = t >> 6;
    #pragma unroll
    for (int rr = 0; rr < 4; ++rr) {
      const int r = (g >> 1) * 4 + rr;
      float* orow = P.out + ((size_t)bid * NROWS + r) * RSTRIDE;
      const float* cb = P.codebook + (size_t)s_idx[r] * 128;
      if ((g & 1) == 0) {
        float z = s_zr[r][j];
        orow[j] = z + (cb[j] - z);
      } else {
        float z = s_zi[r][j];
        orow[64 + j] = z + (cb[64 + j] - z);
      }
    }
  }
  if (t < NROWS) {
    P.out[OFF_VQLOSS + (size_t)bid * NROWS + t] = s_vqls[t];
    P.out[OFF_IDX + (size_t)bid * NROWS + t] = (float)s_idx[t];
  }
}

// ================= lin_kernel: clinears + gate + palettes =================
union __align__(16) ScratchL {
  float w[64][64];                                                // 16 KB staged weights
  struct { float vis[NROWS][128]; float palp[NROWS][32]; } pal;   // 5 KB
};

__global__ void lin_kernel(Params P) {
  const int t = threadIdx.x;
  const int bid = blockIdx.x;

  __shared__ __align__(16) float s_zr[NROWS][64], s_zi[NROWS][64];
  __shared__ ScratchL u;
  __shared__ float s_qr[NROWS][64], s_qi[NROWS][64];
  __shared__ float s_kr[NROWS][64], s_ki[NROWS][64];
  __shared__ float s_vr[NROWS][64], s_vi[NROWS][64];
  __shared__ __align__(16) float s_sf[NROWS][128];
  __shared__ float s_gate[NROWS];

  // P0: stage z
  {
    const float* cr = P.curr_r + (size_t)bid * (NROWS * 64);
    const float* ci = P.curr_i + (size_t)bid * (NROWS * 64);
    float* zr = &s_zr[0][0];
    float* zi = &s_zi[0][0];
    for (int i = t; i < NROWS * 64; i += 256) { zr[i] = cr[i]; zi[i] = ci[i]; }
  }
  __syncthreads();

  // P2: five complex linears (verified)
  {
    const int j = t & 63, rg = t >> 6;
    const float* Wr_tab[5] = {P.qkv_Wr, P.qkv_Wr + 4096, P.qkv_Wr + 8192, P.quad_Wr, P.sens_Wr};
    const float* Wi_tab[5] = {P.qkv_Wi, P.qkv_Wi + 4096, P.qkv_Wi + 8192, P.quad_Wi, P.sens_Wi};
    const float* br_tab[5] = {P.qkv_br, P.qkv_br + 64, P.qkv_br + 128, P.quad_br, P.sens_br};
    const float* bi_tab[5] = {P.qkv_bi, P.qkv_bi + 64, P.qkv_bi + 128, P.quad_bi, P.sens_bi};
    #pragma unroll 1
    for (int cl = 0; cl < 5; ++cl) {
      __syncthreads();
      { const float4* src = (const float4*)Wr_tab[cl];
        float4* dst = (float4*)&u.w[0][0];
        for (int i = t; i < 1024; i += 256) dst[i] = src[i]; }
      __syncthreads();
      float aRR0 = 0.f, aRR1 = 0.f, aIR0 = 0.f, aIR1 = 0.f;
      for (int d4 = 0; d4 < 64; d4 += 4) {
        float4 zr0 = *(const float4*)&s_zr[rg][d4];
        float4 zr1 = *(const float4*)&s_zr[rg + 4][d4];
        float4 zi0 = *(const float4*)&s_zi[rg][d4];
        float4 zi1 = *(const float4*)&s_zi[rg + 4][d4];
        float w0 = u.w[d4 + 0][j], w1 = u.w[d4 + 1][j];
        float w2 = u.w[d4 + 2][j], w3 = u.w[d4 + 3][j];
        aRR0 += zr0.x * w0 + zr0.y * w1 + zr0.z * w2 + zr0.w * w3;
        aRR1 += zr1.x * w0 + zr1.y * w1 + zr1.z * w2 + zr1.w * w3;
        aIR0 += zi0.x * w0 + zi0.y * w1 + zi0.z * w2 + zi0.w * w3;
        aIR1 += zi1.x * w0 + zi1.y * w1 + zi1.z * w2 + zi1.w * w3;
      }
      __syncthreads();
      { const float4* src = (const float4*)Wi_tab[cl];
        float4* dst = (float4*)&u.w[0][0];
        for (int i = t; i < 1024; i += 256) dst[i] = src[i]; }
      __syncthreads();
      float aRI0 = 0.f, aRI1 = 0.f, aII0 = 0.f, aII1 = 0.f;
      for (int d4 = 0; d4 < 64; d4 += 4) {
        float4 zr0 = *(const float4*)&s_zr[rg][d4];
        float4 zr1 = *(const float4*)&s_zr[rg + 4][d4];
        float4 zi0 = *(const float4*)&s_zi[rg][d4];
        float4 zi1 = *(const float4*)&s_zi[rg + 4][d4];
        float w0 = u.w[d4 + 0][j], w1 = u.w[d4 + 1][j];
        float w2 = u.w[d4 + 2][j], w3 = u.w[d4 + 3][j];
        aRI0 += zr0.x * w0 + zr0.y * w1 + zr0.z * w2 + zr0.w * w3;
        aRI1 += zr1.x * w0 + zr1.y * w1 + zr1.z * w2 + zr1.w * w3;
        aII0 += zi0.x * w0 + zi0.y * w1 + zi0.z * w2 + zi0.w * w3;
        aII1 += zi1.x * w0 + zi1.y * w1 + zi1.z * w2 + zi1.w * w3;
      }
      const float brj = br_tab[cl][j], bij = bi_tab[cl][j];
      #pragma unroll
      for (int hh = 0; hh < 2; ++hh) {
        const int r = rg + hh * 4;
        const float pRR = hh ? aRR1 : aRR0;
        const float pII = hh ? aII1 : aII0;
        const float pRI = hh ? aRI1 : aRI0;
        const float pIR = hh ? aIR1 : aIR0;
        const float oR = (pRR + brj) - (pII + bij);
        const float oI = (pRI + bij) + (pIR + brj);
        if (cl == 0)      { s_qr[r][j] = oR; s_qi[r][j] = oI; }
        else if (cl == 1) { s_kr[r][j] = oR; s_ki[r][j] = oI; }
        else if (cl == 2) { s_vr[r][j] = oR; s_vi[r][j] = oI; }
        else if (cl == 3) {
          float* orow = P.out + ((size_t)bid * NROWS + r) * RSTRIDE;
          orow[512 + j] = -oI;
          orow[576 + j] = oR;
        } else            { s_sf[r][j] = oR; s_sf[r][64 + j] = oI; }
      }
    }
    __syncthreads();
  }

  // P3: gate (verified)
  {
    const int r = t >> 5, l = t & 31;
    float g = s_qr[r][l] * s_kr[r][l] + s_qi[r][l] * s_ki[r][l]
            + s_qr[r][l + 32] * s_kr[r][l + 32] + s_qi[r][l + 32] * s_ki[r][l + 32];
    #pragma unroll
    for (int m = 16; m >= 1; m >>= 1) g += __shfl_xor(g, m);
    if (l == 0) s_gate[r] = 1.f / (1.f + expf(-g));
  }
  __syncthreads();

  // P5: palette attends (verified)
  {
    const int r = t >> 5, a = t & 31;
    float sc = 0.f;
    for (int jj = 0; jj < 128; jj += 4) {
      const float4 sf = *(const float4*)&s_sf[r][jj];
      const float4 pv = *(const float4*)&P.vis_pal[a * 128 + jj];
      sc += sf.x * pv.x + sf.y * pv.y + sf.z * pv.z + sf.w * pv.w;
    }
    float mx = sc;
    #pragma unroll
    for (int m = 16; m >= 1; m >>= 1) mx = fmaxf(mx, __shfl_xor(mx, m));
    float e = expf(sc - mx);
    float sm = e;
    #pragma unroll
    for (int m = 16; m >= 1; m >>= 1) sm += __shfl_xor(sm, m);
    u.pal.palp[r][a] = e / sm;
  }
  __syncthreads();
  {
    const int j = t & 127, rp = t >> 7;
    float acc[4] = {0.f, 0.f, 0.f, 0.f};
    for (int a = 0; a < 32; ++a) {
      const float pv = P.vis_pal[a * 128 + j];
      #pragma unroll
      for (int q = 0; q < 4; ++q) acc[q] += u.pal.palp[rp + q * 2][a] * pv;
    }
    #pragma unroll
    for (int q = 0; q < 4; ++q) u.pal.vis[rp + q * 2][j] = acc[q];
  }
  __syncthreads();
  {
    const int r = t >> 5, a = t & 31;
    float sc = 0.f;
    for (int jj = 0; jj < 128; jj += 4) {
      const float4 sf = *(const float4*)&s_sf[r][jj];
      const float4 pv = *(const float4*)&P.aud_pal[a * 128 + jj];
      sc += sf.x * pv.x + sf.y * pv.y + sf.z * pv.z + sf.w * pv.w;
    }
    float mx = sc;
    #pragma unroll
    for (int m = 16; m >= 1; m >>= 1) mx = fmaxf(mx, __shfl_xor(mx, m));
    float e = expf(sc - mx);
    float sm = e;
    #pragma unroll
    for (int m = 16; m >= 1; m >>= 1) sm += __shfl_xor(sm, m);
    u.pal.palp[r][a] = e / sm;
  }
  __syncthreads();
  {
    const int j = t & 127, rp = t >> 7;
    float acc[4] = {0.f, 0.f, 0.f, 0.f};
    for (int a = 0; a < 32; ++a) {
      const float pv = P.aud_pal[a * 128 + j];
      #pragma unroll
      for (int q = 0; q < 4; ++q) acc[q] += u.pal.palp[rp + q * 2][a] * pv;
    }
    #pragma unroll
    for (int q = 0; q < 4; ++q) {
      const int rr = rp + q * 2;
      const size_t bb = (size_t)bid * NROWS + rr;
      float* orow = P.out + bb * RSTRIDE;
      if (j < 64) orow[448 + j] = u.pal.vis[rr][64 + j] + acc[q];        // exp_i
      else        orow[384 + (j - 64)] = u.pal.vis[rr][j - 64] - acc[q]; // exp_r
    }
  }

  // g_r/g_i writes
  {
    const int j = t & 63, g = t >> 6;
    #pragma unroll
    for (int rr = 0; rr < 4; ++rr) {
      const int r = (g >> 1) * 4 + rr;
      float* orow = P.out + ((size_t)bid * NROWS + r) * RSTRIDE;
      if ((g & 1) == 0) orow[128 + j] = s_vr[r][j] * s_gate[r];
      else              orow[192 + j] = s_vi[r][j] * s_gate[r];
    }
  }
}

// ================= mem_kernel: unchanged from passing R8 =================
__global__ __launch_bounds__(256, 4) void mem_kernel(Params P) {
  const int b = blockIdx.x;
  const int t = threadIdx.x;
  const int lane = t & 63;
  const int wv = t >> 6;

  __shared__ float zr[64], zi[64];
  __shared__ float lp[4][32];
  __shared__ float s_eff[32];
  __shared__ float s_sim[32], s_attn[32];
  __shared__ float s_rr[4][8][8], s_ri[4][8][8];
  __shared__ float s_wg;

  if (t < 64)       zr[t]      = P.curr_r[(size_t)b * 64 + t];
  else if (t < 128) zi[t - 64] = P.curr_i[(size_t)b * 64 + (t - 64)];
  __syncthreads();

  const size_t bb = (size_t)b;
  const int s = t >> 3, k = t & 7, d0 = k * 8;
  const float* mrp = P.mem_r + ((bb * 32 + s) * 64 + d0);
  const float* mip = P.mem_i + ((bb * 32 + s) * 64 + d0);
  float4 a0 = *(const float4*)mrp, a1 = *(const float4*)(mrp + 4);
  float4 b0 = *(const float4*)mip, b1 = *(const float4*)(mip + 4);
  float mr[8] = {a0.x, a0.y, a0.z, a0.w, a1.x, a1.y, a1.z, a1.w};
  float mi[8] = {b0.x, b0.y, b0.z, b0.w, b1.x, b1.y, b1.z, b1.w};

  if (t < 128) {
    const int q = t >> 5, l = t & 31;
    const float* zz = (q < 2) ? zr : zi;
    const int zb = (q & 1) * 32;
    float a = 0.f;
    for (int i = 0; i < 32; ++i) a += zz[zb + i] * P.addr_W[(q * 32 + i) * 32 + l];
    lp[q][l] = a;
  } else if (t < 192) {
    const int j = t - 128;
    float tw = zr[j] * P.gate_W[j] + zi[j] * P.gate_W[64 + j];
    #pragma unroll
    for (int m = 1; m <= 32; m <<= 1) tw += __shfl_xor(tw, m);
    if (j == 0) s_wg = tw;
  }

  float sp = 0.f;
  #pragma unroll
  for (int x = 0; x < 8; ++x) sp += mr[x] * zr[d0 + x] + mi[x] * zi[d0 + x];
  sp += __shfl_xor(sp, 1); sp += __shfl_xor(sp, 2); sp += __shfl_xor(sp, 4);
  if (k == 0) s_sim[s] = sp;
  __syncthreads();

  if (t < 32) {
    float v = s_sim[t];
    float mx = v;
    #pragma unroll
    for (int m = 16; m >= 1; m >>= 1) mx = fmaxf(mx, __shfl_xor(mx, m));
    float e = expf(v - mx);
    float sm = e;
    #pragma unroll
    for (int m = 16; m >= 1; m >>= 1) sm += __shfl_xor(sm, m);
    s_attn[t] = e / sm;
  } else if (t >= 64 && t < 96) {
    const int l = t - 64;
    float lg = lp[0][l] + lp[1][l] + lp[2][l] + lp[3][l] + P.addr_b[l];
    float mx = lg;
    #pragma unroll
    for (int m = 16; m >= 1; m >>= 1) mx = fmaxf(mx, __shfl_xor(mx, m));
    float e = expf(lg - mx);
    float sm = e;
    #pragma unroll
    for (int m = 16; m >= 1; m >>= 1) sm += __shfl_xor(sm, m);
    const float w = e / sm;
    float es = -(w * logf(w + 1e-10f));
    #pragma unroll
    for (int m = 16; m >= 1; m >>= 1) es += __shfl_xor(es, m);
    if (l == 0) P.rowent[b] = es;
    const float myw = w;
    bool picked = false;
    float val = w; int idx = l;
    float sumtop = 0.f;
    #pragma unroll
    for (int it = 0; it < 3; ++it) {
      float v2 = val; int i2 = idx;
      #pragma unroll
      for (int m = 16; m >= 1; m >>= 1) {
        float ov = __shfl_xor(v2, m); int oi = __shfl_xor(i2, m);
        if (ov > v2 || (ov == v2 && oi < i2)) { v2 = ov; i2 = oi; }
      }
      sumtop += v2;
      if (l == i2) { picked = true; val = -1e30f; }
    }
    const float wgate = 1.f / (1.f + expf(-(s_wg + P.gate_b[0])));
    s_eff[l] = picked ? wgate * (myw / (sumtop + 1e-6f)) : 0.f;
  }
  __syncthreads();

  const float aw = s_attn[s];
  {
    float pr[8], pi[8];
    #pragma unroll
    for (int x = 0; x < 8; ++x) { pr[x] = aw * mr[x]; pi[x] = aw * mi[x]; }
    #pragma unroll
    for (int m = 8; m <= 32; m <<= 1) {
      #pragma unroll
      for (int x = 0; x < 8; ++x) { pr[x] += __shfl_xor(pr[x], m); pi[x] += __shfl_xor(pi[x], m); }
    }
    if (lane < 8) {
      #pragma unroll
      for (int x = 0; x < 8; ++x) { s_rr[wv][lane][x] = pr[x]; s_ri[wv][lane][x] = pi[x]; }
    }
  }
  {
    const float eff = s_eff[s];
    float nr[8], ni[8];
    #pragma unroll
    for (int x = 0; x < 8; ++x) {
      nr[x] = tanhf(mr[x] + eff * (zr[d0 + x] - mr[x]));
      ni[x] = tanhf(mi[x] + eff * (zi[d0 + x] - mi[x]));
    }
    float sR = 0.f, sI = 0.f;
    #pragma unroll
    for (int x = 0; x < 8; ++x) { sR += nr[x]; sI += ni[x]; }
    sR += __shfl_xor(sR, 1); sR += __shfl_xor(sR, 2); sR += __shfl_xor(sR, 4);
    sI += __shfl_xor(sI, 1); sI += __shfl_xor(sI, 2); sI += __shfl_xor(sI, 4);
    const float mR = sR * (1.f / 64.f), mI = sI * (1.f / 64.f);
    float vR = 0.f, vI = 0.f;
    #pragma unroll
    for (int x = 0; x < 8; ++x) {
      float dr = nr[x] - mR; vR += dr * dr;
      float di = ni[x] - mI; vI += di * di;
    }
    vR += __shfl_xor(vR, 1); vR += __shfl_xor(vR, 2); vR += __shfl_xor(vR, 4);
    vI += __shfl_xor(vI, 1); vI += __shfl_xor(vI, 2); vI += __shfl_xor(vI, 4);
    const float invR = 1.f / sqrtf(vR * (1.f / 64.f) + 1e-6f);
    const float invI = 1.f / sqrtf(vI * (1.f / 64.f) + 1e-6f);
    float* orow = P.out + bb * RSTRIDE;
    float oR[8], oI[8];
    #pragma unroll
    for (int x = 0; x < 8; ++x) {
      const int d = d0 + x;
      oR[x] = (nr[x] - mR) * invR * P.ln_gr[d] + P.ln_br[d];
      oI[x] = (ni[x] - mI) * invI * P.ln_gi[d] + P.ln_bi[d];
    }
    *(float4*)&orow[640 + s * 64 + d0]      = make_float4(oR[0], oR[1], oR[2], oR[3]);
    *(float4*)&orow[640 + s * 64 + d0 + 4]  = make_float4(oR[4], oR[5], oR[6], oR[7]);
    *(float4*)&orow[2688 + s * 64 + d0]     = make_float4(oI[0], oI[1], oI[2], oI[3]);
    *(float4*)&orow[2688 + s * 64 + d0 + 4] = make_float4(oI[4], oI[5], oI[6], oI[7]);
  }
  __syncthreads();
  if (t < 64) {
    const int kk = t >> 3, xx = t & 7;
    float rv = s_rr[0][kk][xx] + s_rr[1][kk][xx] + s_rr[2][kk][xx] + s_rr[3][kk][xx];
    float iv = s_ri[0][kk][xx] + s_ri[1][kk][xx] + s_ri[2][kk][xx] + s_ri[3][kk][xx];
    float* orow = P.out + bb * RSTRIDE;
    orow[256 + t] = rv;
    orow[320 + t] = iv;
  }
}

__global__ __launch_bounds__(256) void finalize_k(const int* hist, const float* rowent,
                                                  float* out) {
  const int t = threadIdx.x;
  __shared__ float red[256];
  float se = 0.f;
  for (int i = t; i < 8192; i += 256) se += rowent[i];
  red[t] = se;
  __syncthreads();
  for (int off = 128; off >= 1; off >>= 1) {
    if (t < off) red[t] += red[t + off];
    __syncthreads();
  }
  if (t == 0) out[OFF_SENT] = red[0] / 8192.0f;
  __syncthreads();
  float ne = 0.f;
  if (t < 128) {
    const float pp = (float)hist[t] / 8192.0f;
    ne = -(pp * logf(pp + 1e-10f));
  }
  red[t] = ne;
  __syncthreads();
  for (int off = 128; off >= 1; off >>= 1) {
    if (t < off) red[t] += red[t + off];
    __syncthreads();
  }
  if (t == 0) out[OFF_NENT] = red[0] / logf(128.0f);
}

extern "C" void kernel_launch(void* const* d_in, const int* in_sizes, int n_in,
                              void* d_out, int out_size, void* d_ws, size_t ws_size,
                              hipStream_t stream) {
  (void)in_sizes; (void)n_in; (void)out_size; (void)ws_size;
  Params P;
  P.curr_r   = (const float*)d_in[0];
  P.curr_i   = (const float*)d_in[1];
  P.mem_r    = (const float*)d_in[2];
  P.mem_i    = (const float*)d_in[3];
  P.codebook = (const float*)d_in[4];
  P.qkv_Wr   = (const float*)d_in[5];
  P.qkv_Wi   = (const float*)d_in[6];
  P.qkv_br   = (const float*)d_in[7];
  P.qkv_bi   = (const float*)d_in[8];
  P.quad_Wr  = (const float*)d_in[9];
  P.quad_Wi  = (const float*)d_in[10];
  P.quad_br  = (const float*)d_in[11];
  P.quad_bi  = (const float*)d_in[12];
  P.sens_Wr  = (const float*)d_in[13];
  P.sens_Wi  = (const float*)d_in[14];
  P.sens_br  = (const float*)d_in[15];
  P.sens_bi  = (const float*)d_in[16];
  P.vis_pal  = (const float*)d_in[17];
  P.aud_pal  = (const float*)d_in[18];
  P.gate_W   = (const float*)d_in[19];
  P.gate_b   = (const float*)d_in[20];
  P.addr_W   = (const float*)d_in[21];
  P.addr_b   = (const float*)d_in[22];
  P.ln_gr    = (const float*)d_in[23];
  P.ln_br    = (const float*)d_in[24];
  P.ln_gi    = (const float*)d_in[25];
  P.ln_bi    = (const float*)d_in[26];
  P.out = (float*)d_out;
  P.hist = (int*)d_ws;
  P.rowent = (float*)((char*)d_ws + 512);

  hipMemsetAsync(d_ws, 0, 512, stream);
  mem_kernel<<<dim3(8192), dim3(256), 0, stream>>>(P);
  vq_kernel<<<dim3(NBLOCKS), dim3(256), 0, stream>>>(P);
  lin_kernel<<<dim3(NBLOCKS), dim3(256), 0, stream>>>(P);
  finalize_k<<<dim3(1), dim3(256), 0, stream>>>(P.hist, P.rowent, (float*)d_out);
}

// Round 11
// 266.906 us; speedup vs baseline: 3.5532x; 3.5449x over previous
//
#include <hip/hip_runtime.h>
#include <hip/hip_bf16.h>

// SACRSN_v84 — v11: R10 + __launch_bounds__(256) on vq/lin kernels.
// R10 lesson: no launch_bounds => hipcc assumes 1024-thread blocks => VGPR<=64
// => scratch spill (2.7 GB traffic). Plain (256) allows ~212 VGPR, no spill (R8).

#define NROWS 8
#define NBLOCKS 1024
#define RSTRIDE 4736

static constexpr size_t OFF_VQLOSS = 38797312UL;  // 8192*4736
static constexpr size_t OFF_IDX    = 38805504UL;
static constexpr size_t OFF_SENT   = 38813696UL;
static constexpr size_t OFF_NENT   = 38813697UL;

struct Params {
  const float* curr_r; const float* curr_i;
  const float* mem_r;  const float* mem_i;
  const float* codebook;
  const float* qkv_Wr; const float* qkv_Wi; const float* qkv_br; const float* qkv_bi;
  const float* quad_Wr; const float* quad_Wi; const float* quad_br; const float* quad_bi;
  const float* sens_Wr; const float* sens_Wi; const float* sens_br; const float* sens_bi;
  const float* vis_pal; const float* aud_pal;
  const float* gate_W; const float* gate_b;
  const float* addr_W; const float* addr_b;
  const float* ln_gr; const float* ln_br; const float* ln_gi; const float* ln_bi;
  float* out;
  int* hist;          // ws: 128 ints
  float* rowent;      // ws + 512 B: 8192 floats
};

// ================= vq_kernel: VQ argmin + vq/indices/vq_loss =================
__global__ __launch_bounds__(256) void vq_kernel(Params P) {
  const int t = threadIdx.x;
  const int bid = blockIdx.x;
  const int lane = t & 63;
  const int wv = t >> 6;

  __shared__ __align__(16) float s_zr[NROWS][64], s_zi[NROWS][64];
  __shared__ double s_cbn[128];
  __shared__ double s_dall[NROWS][256];
  __shared__ float s_vqls[NROWS];
  __shared__ int s_idx[NROWS];

  // P0: stage z
  {
    const float* cr = P.curr_r + (size_t)bid * (NROWS * 64);
    const float* ci = P.curr_i + (size_t)bid * (NROWS * 64);
    float* zr = &s_zr[0][0];
    float* zi = &s_zi[0][0];
    for (int i = t; i < NROWS * 64; i += 256) { zr[i] = cr[i]; zi[i] = ci[i]; }
  }

  // P0b: codebook squared norms (f64)
  {
    const float* cb = P.codebook + (t & 127) * 128 + (t >> 7) * 64;
    double a = 0.0;
    for (int d = 0; d < 64; ++d) { double w = (double)cb[d]; a = fma(w, w, a); }
    s_dall[0][t] = a;
    __syncthreads();
    if (t < 128) s_cbn[t] = s_dall[0][t] + s_dall[0][t + 128];
    __syncthreads();
  }

  // P1: VQ argmin — all rows parallel (verified R9/R10)
  {
    const int c = t & 127, h = t >> 7;
    const float* cb = P.codebook + c * 128 + h * 64;
    const float (*zb)[64] = h ? s_zi : s_zr;
    double acc[NROWS];
    #pragma unroll
    for (int r = 0; r < NROWS; ++r) acc[r] = 0.0;
    for (int d = 0; d < 64; ++d) {
      const double w = (double)cb[d];
      #pragma unroll
      for (int r = 0; r < NROWS; ++r) acc[r] = fma(w, (double)zb[r][d], acc[r]);
    }
    #pragma unroll
    for (int r = 0; r < NROWS; ++r) s_dall[r][h * 128 + c] = acc[r];
    __syncthreads();
    #pragma unroll
    for (int rr = 0; rr < 2; ++rr) {
      const int r = wv * 2 + rr;
      const double d0 = s_cbn[lane]      - 2.0 * (s_dall[r][lane]      + s_dall[r][128 + lane]);
      const double d1 = s_cbn[lane + 64] - 2.0 * (s_dall[r][64 + lane] + s_dall[r][192 + lane]);
      double sv = d0; int si = lane;
      if (d1 < sv) { sv = d1; si = lane + 64; }
      #pragma unroll
      for (int m = 1; m <= 32; m <<= 1) {
        double ov = __shfl_xor(sv, m);
        int oi = __shfl_xor(si, m);
        if (ov < sv || (ov == sv && oi < si)) { sv = ov; si = oi; }
      }
      if (lane == 0) { s_idx[r] = si; atomicAdd(&P.hist[si], 1); }
    }
    __syncthreads();
  }

  // P1b: vq_loss (verified)
  {
    #pragma unroll
    for (int rr = 0; rr < 2; ++rr) {
      const int r = wv * 2 + rr;
      const float* cb = P.codebook + (size_t)s_idx[r] * 128;
      float d0_ = cb[lane] - s_zr[r][lane];
      float d1_ = cb[64 + lane] - s_zi[r][lane];
      float v = d0_ * d0_ + d1_ * d1_;
      #pragma unroll
      for (int m = 1; m <= 32; m <<= 1) v += __shfl_xor(v, m);
      if (lane == 0) s_vqls[r] = 0.25f * v * (1.0f / 128.0f);
    }
  }
  __syncthreads();

  // vq_r/vq_i straight-through writes
  {
    const int j = t & 63, g = t >> 6;
    #pragma unroll
    for (int rr = 0; rr < 4; ++rr) {
      const int r = (g >> 1) * 4 + rr;
      float* orow = P.out + ((size_t)bid * NROWS + r) * RSTRIDE;
      const float* cb = P.codebook + (size_t)s_idx[r] * 128;
      if ((g & 1) == 0) {
        float z = s_zr[r][j];
        orow[j] = z + (cb[j] - z);
      } else {
        float z = s_zi[r][j];
        orow[64 + j] = z + (cb[64 + j] - z);
      }
    }
  }
  if (t < NROWS) {
    P.out[OFF_VQLOSS + (size_t)bid * NROWS + t] = s_vqls[t];
    P.out[OFF_IDX + (size_t)bid * NROWS + t] = (float)s_idx[t];
  }
}

// ================= lin_kernel: clinears + gate + palettes =================
union __align__(16) ScratchL {
  float w[64][64];                                                // 16 KB staged weights
  struct { float vis[NROWS][128]; float palp[NROWS][32]; } pal;   // 5 KB
};

__global__ __launch_bounds__(256) void lin_kernel(Params P) {
  const int t = threadIdx.x;
  const int bid = blockIdx.x;

  __shared__ __align__(16) float s_zr[NROWS][64], s_zi[NROWS][64];
  __shared__ ScratchL u;
  __shared__ float s_qr[NROWS][64], s_qi[NROWS][64];
  __shared__ float s_kr[NROWS][64], s_ki[NROWS][64];
  __shared__ float s_vr[NROWS][64], s_vi[NROWS][64];
  __shared__ __align__(16) float s_sf[NROWS][128];
  __shared__ float s_gate[NROWS];

  // P0: stage z
  {
    const float* cr = P.curr_r + (size_t)bid * (NROWS * 64);
    const float* ci = P.curr_i + (size_t)bid * (NROWS * 64);
    float* zr = &s_zr[0][0];
    float* zi = &s_zi[0][0];
    for (int i = t; i < NROWS * 64; i += 256) { zr[i] = cr[i]; zi[i] = ci[i]; }
  }
  __syncthreads();

  // P2: five complex linears (verified)
  {
    const int j = t & 63, rg = t >> 6;
    const float* Wr_tab[5] = {P.qkv_Wr, P.qkv_Wr + 4096, P.qkv_Wr + 8192, P.quad_Wr, P.sens_Wr};
    const float* Wi_tab[5] = {P.qkv_Wi, P.qkv_Wi + 4096, P.qkv_Wi + 8192, P.quad_Wi, P.sens_Wi};
    const float* br_tab[5] = {P.qkv_br, P.qkv_br + 64, P.qkv_br + 128, P.quad_br, P.sens_br};
    const float* bi_tab[5] = {P.qkv_bi, P.qkv_bi + 64, P.qkv_bi + 128, P.quad_bi, P.sens_bi};
    #pragma unroll 1
    for (int cl = 0; cl < 5; ++cl) {
      __syncthreads();
      { const float4* src = (const float4*)Wr_tab[cl];
        float4* dst = (float4*)&u.w[0][0];
        for (int i = t; i < 1024; i += 256) dst[i] = src[i]; }
      __syncthreads();
      float aRR0 = 0.f, aRR1 = 0.f, aIR0 = 0.f, aIR1 = 0.f;
      for (int d4 = 0; d4 < 64; d4 += 4) {
        float4 zr0 = *(const float4*)&s_zr[rg][d4];
        float4 zr1 = *(const float4*)&s_zr[rg + 4][d4];
        float4 zi0 = *(const float4*)&s_zi[rg][d4];
        float4 zi1 = *(const float4*)&s_zi[rg + 4][d4];
        float w0 = u.w[d4 + 0][j], w1 = u.w[d4 + 1][j];
        float w2 = u.w[d4 + 2][j], w3 = u.w[d4 + 3][j];
        aRR0 += zr0.x * w0 + zr0.y * w1 + zr0.z * w2 + zr0.w * w3;
        aRR1 += zr1.x * w0 + zr1.y * w1 + zr1.z * w2 + zr1.w * w3;
        aIR0 += zi0.x * w0 + zi0.y * w1 + zi0.z * w2 + zi0.w * w3;
        aIR1 += zi1.x * w0 + zi1.y * w1 + zi1.z * w2 + zi1.w * w3;
      }
      __syncthreads();
      { const float4* src = (const float4*)Wi_tab[cl];
        float4* dst = (float4*)&u.w[0][0];
        for (int i = t; i < 1024; i += 256) dst[i] = src[i]; }
      __syncthreads();
      float aRI0 = 0.f, aRI1 = 0.f, aII0 = 0.f, aII1 = 0.f;
      for (int d4 = 0; d4 < 64; d4 += 4) {
        float4 zr0 = *(const float4*)&s_zr[rg][d4];
        float4 zr1 = *(const float4*)&s_zr[rg + 4][d4];
        float4 zi0 = *(const float4*)&s_zi[rg][d4];
        float4 zi1 = *(const float4*)&s_zi[rg + 4][d4];
        float w0 = u.w[d4 + 0][j], w1 = u.w[d4 + 1][j];
        float w2 = u.w[d4 + 2][j], w3 = u.w[d4 + 3][j];
        aRI0 += zr0.x * w0 + zr0.y * w1 + zr0.z * w2 + zr0.w * w3;
        aRI1 += zr1.x * w0 + zr1.y * w1 + zr1.z * w2 + zr1.w * w3;
        aII0 += zi0.x * w0 + zi0.y * w1 + zi0.z * w2 + zi0.w * w3;
        aII1 += zi1.x * w0 + zi1.y * w1 + zi1.z * w2 + zi1.w * w3;
      }
      const float brj = br_tab[cl][j], bij = bi_tab[cl][j];
      #pragma unroll
      for (int hh = 0; hh < 2; ++hh) {
        const int r = rg + hh * 4;
        const float pRR = hh ? aRR1 : aRR0;
        const float pII = hh ? aII1 : aII0;
        const float pRI = hh ? aRI1 : aRI0;
        const float pIR = hh ? aIR1 : aIR0;
        const float oR = (pRR + brj) - (pII + bij);
        const float oI = (pRI + bij) + (pIR + brj);
        if (cl == 0)      { s_qr[r][j] = oR; s_qi[r][j] = oI; }
        else if (cl == 1) { s_kr[r][j] = oR; s_ki[r][j] = oI; }
        else if (cl == 2) { s_vr[r][j] = oR; s_vi[r][j] = oI; }
        else if (cl == 3) {
          float* orow = P.out + ((size_t)bid * NROWS + r) * RSTRIDE;
          orow[512 + j] = -oI;
          orow[576 + j] = oR;
        } else            { s_sf[r][j] = oR; s_sf[r][64 + j] = oI; }
      }
    }
    __syncthreads();
  }

  // P3: gate (verified)
  {
    const int r = t >> 5, l = t & 31;
    float g = s_qr[r][l] * s_kr[r][l] + s_qi[r][l] * s_ki[r][l]
            + s_qr[r][l + 32] * s_kr[r][l + 32] + s_qi[r][l + 32] * s_ki[r][l + 32];
    #pragma unroll
    for (int m = 16; m >= 1; m >>= 1) g += __shfl_xor(g, m);
    if (l == 0) s_gate[r] = 1.f / (1.f + expf(-g));
  }
  __syncthreads();

  // P5: palette attends (verified)
  {
    const int r = t >> 5, a = t & 31;
    float sc = 0.f;
    for (int jj = 0; jj < 128; jj += 4) {
      const float4 sf = *(const float4*)&s_sf[r][jj];
      const float4 pv = *(const float4*)&P.vis_pal[a * 128 + jj];
      sc += sf.x * pv.x + sf.y * pv.y + sf.z * pv.z + sf.w * pv.w;
    }
    float mx = sc;
    #pragma unroll
    for (int m = 16; m >= 1; m >>= 1) mx = fmaxf(mx, __shfl_xor(mx, m));
    float e = expf(sc - mx);
    float sm = e;
    #pragma unroll
    for (int m = 16; m >= 1; m >>= 1) sm += __shfl_xor(sm, m);
    u.pal.palp[r][a] = e / sm;
  }
  __syncthreads();
  {
    const int j = t & 127, rp = t >> 7;
    float acc[4] = {0.f, 0.f, 0.f, 0.f};
    for (int a = 0; a < 32; ++a) {
      const float pv = P.vis_pal[a * 128 + j];
      #pragma unroll
      for (int q = 0; q < 4; ++q) acc[q] += u.pal.palp[rp + q * 2][a] * pv;
    }
    #pragma unroll
    for (int q = 0; q < 4; ++q) u.pal.vis[rp + q * 2][j] = acc[q];
  }
  __syncthreads();
  {
    const int r = t >> 5, a = t & 31;
    float sc = 0.f;
    for (int jj = 0; jj < 128; jj += 4) {
      const float4 sf = *(const float4*)&s_sf[r][jj];
      const float4 pv = *(const float4*)&P.aud_pal[a * 128 + jj];
      sc += sf.x * pv.x + sf.y * pv.y + sf.z * pv.z + sf.w * pv.w;
    }
    float mx = sc;
    #pragma unroll
    for (int m = 16; m >= 1; m >>= 1) mx = fmaxf(mx, __shfl_xor(mx, m));
    float e = expf(sc - mx);
    float sm = e;
    #pragma unroll
    for (int m = 16; m >= 1; m >>= 1) sm += __shfl_xor(sm, m);
    u.pal.palp[r][a] = e / sm;
  }
  __syncthreads();
  {
    const int j = t & 127, rp = t >> 7;
    float acc[4] = {0.f, 0.f, 0.f, 0.f};
    for (int a = 0; a < 32; ++a) {
      const float pv = P.aud_pal[a * 128 + j];
      #pragma unroll
      for (int q = 0; q < 4; ++q) acc[q] += u.pal.palp[rp + q * 2][a] * pv;
    }
    #pragma unroll
    for (int q = 0; q < 4; ++q) {
      const int rr = rp + q * 2;
      const size_t bb = (size_t)bid * NROWS + rr;
      float* orow = P.out + bb * RSTRIDE;
      if (j < 64) orow[448 + j] = u.pal.vis[rr][64 + j] + acc[q];        // exp_i
      else        orow[384 + (j - 64)] = u.pal.vis[rr][j - 64] - acc[q]; // exp_r
    }
  }

  // g_r/g_i writes
  {
    const int j = t & 63, g = t >> 6;
    #pragma unroll
    for (int rr = 0; rr < 4; ++rr) {
      const int r = (g >> 1) * 4 + rr;
      float* orow = P.out + ((size_t)bid * NROWS + r) * RSTRIDE;
      if ((g & 1) == 0) orow[128 + j] = s_vr[r][j] * s_gate[r];
      else              orow[192 + j] = s_vi[r][j] * s_gate[r];
    }
  }
}

// ================= mem_kernel: unchanged from passing R8 =================
__global__ __launch_bounds__(256, 4) void mem_kernel(Params P) {
  const int b = blockIdx.x;
  const int t = threadIdx.x;
  const int lane = t & 63;
  const int wv = t >> 6;

  __shared__ float zr[64], zi[64];
  __shared__ float lp[4][32];
  __shared__ float s_eff[32];
  __shared__ float s_sim[32], s_attn[32];
  __shared__ float s_rr[4][8][8], s_ri[4][8][8];
  __shared__ float s_wg;

  if (t < 64)       zr[t]      = P.curr_r[(size_t)b * 64 + t];
  else if (t < 128) zi[t - 64] = P.curr_i[(size_t)b * 64 + (t - 64)];
  __syncthreads();

  const size_t bb = (size_t)b;
  const int s = t >> 3, k = t & 7, d0 = k * 8;
  const float* mrp = P.mem_r + ((bb * 32 + s) * 64 + d0);
  const float* mip = P.mem_i + ((bb * 32 + s) * 64 + d0);
  float4 a0 = *(const float4*)mrp, a1 = *(const float4*)(mrp + 4);
  float4 b0 = *(const float4*)mip, b1 = *(const float4*)(mip + 4);
  float mr[8] = {a0.x, a0.y, a0.z, a0.w, a1.x, a1.y, a1.z, a1.w};
  float mi[8] = {b0.x, b0.y, b0.z, b0.w, b1.x, b1.y, b1.z, b1.w};

  if (t < 128) {
    const int q = t >> 5, l = t & 31;
    const float* zz = (q < 2) ? zr : zi;
    const int zb = (q & 1) * 32;
    float a = 0.f;
    for (int i = 0; i < 32; ++i) a += zz[zb + i] * P.addr_W[(q * 32 + i) * 32 + l];
    lp[q][l] = a;
  } else if (t < 192) {
    const int j = t - 128;
    float tw = zr[j] * P.gate_W[j] + zi[j] * P.gate_W[64 + j];
    #pragma unroll
    for (int m = 1; m <= 32; m <<= 1) tw += __shfl_xor(tw, m);
    if (j == 0) s_wg = tw;
  }

  float sp = 0.f;
  #pragma unroll
  for (int x = 0; x < 8; ++x) sp += mr[x] * zr[d0 + x] + mi[x] * zi[d0 + x];
  sp += __shfl_xor(sp, 1); sp += __shfl_xor(sp, 2); sp += __shfl_xor(sp, 4);
  if (k == 0) s_sim[s] = sp;
  __syncthreads();

  if (t < 32) {
    float v = s_sim[t];
    float mx = v;
    #pragma unroll
    for (int m = 16; m >= 1; m >>= 1) mx = fmaxf(mx, __shfl_xor(mx, m));
    float e = expf(v - mx);
    float sm = e;
    #pragma unroll
    for (int m = 16; m >= 1; m >>= 1) sm += __shfl_xor(sm, m);
    s_attn[t] = e / sm;
  } else if (t >= 64 && t < 96) {
    const int l = t - 64;
    float lg = lp[0][l] + lp[1][l] + lp[2][l] + lp[3][l] + P.addr_b[l];
    float mx = lg;
    #pragma unroll
    for (int m = 16; m >= 1; m >>= 1) mx = fmaxf(mx, __shfl_xor(mx, m));
    float e = expf(lg - mx);
    float sm = e;
    #pragma unroll
    for (int m = 16; m >= 1; m >>= 1) sm += __shfl_xor(sm, m);
    const float w = e / sm;
    float es = -(w * logf(w + 1e-10f));
    #pragma unroll
    for (int m = 16; m >= 1; m >>= 1) es += __shfl_xor(es, m);
    if (l == 0) P.rowent[b] = es;
    const float myw = w;
    bool picked = false;
    float val = w; int idx = l;
    float sumtop = 0.f;
    #pragma unroll
    for (int it = 0; it < 3; ++it) {
      float v2 = val; int i2 = idx;
      #pragma unroll
      for (int m = 16; m >= 1; m >>= 1) {
        float ov = __shfl_xor(v2, m); int oi = __shfl_xor(i2, m);
        if (ov > v2 || (ov == v2 && oi < i2)) { v2 = ov; i2 = oi; }
      }
      sumtop += v2;
      if (l == i2) { picked = true; val = -1e30f; }
    }
    const float wgate = 1.f / (1.f + expf(-(s_wg + P.gate_b[0])));
    s_eff[l] = picked ? wgate * (myw / (sumtop + 1e-6f)) : 0.f;
  }
  __syncthreads();

  const float aw = s_attn[s];
  {
    float pr[8], pi[8];
    #pragma unroll
    for (int x = 0; x < 8; ++x) { pr[x] = aw * mr[x]; pi[x] = aw * mi[x]; }
    #pragma unroll
    for (int m = 8; m <= 32; m <<= 1) {
      #pragma unroll
      for (int x = 0; x < 8; ++x) { pr[x] += __shfl_xor(pr[x], m); pi[x] += __shfl_xor(pi[x], m); }
    }
    if (lane < 8) {
      #pragma unroll
      for (int x = 0; x < 8; ++x) { s_rr[wv][lane][x] = pr[x]; s_ri[wv][lane][x] = pi[x]; }
    }
  }
  {
    const float eff = s_eff[s];
    float nr[8], ni[8];
    #pragma unroll
    for (int x = 0; x < 8; ++x) {
      nr[x] = tanhf(mr[x] + eff * (zr[d0 + x] - mr[x]));
      ni[x] = tanhf(mi[x] + eff * (zi[d0 + x] - mi[x]));
    }
    float sR = 0.f, sI = 0.f;
    #pragma unroll
    for (int x = 0; x < 8; ++x) { sR += nr[x]; sI += ni[x]; }
    sR += __shfl_xor(sR, 1); sR += __shfl_xor(sR, 2); sR += __shfl_xor(sR, 4);
    sI += __shfl_xor(sI, 1); sI += __shfl_xor(sI, 2); sI += __shfl_xor(sI, 4);
    const float mR = sR * (1.f / 64.f), mI = sI * (1.f / 64.f);
    float vR = 0.f, vI = 0.f;
    #pragma unroll
    for (int x = 0; x < 8; ++x) {
      float dr = nr[x] - mR; vR += dr * dr;
      float di = ni[x] - mI; vI += di * di;
    }
    vR += __shfl_xor(vR, 1); vR += __shfl_xor(vR, 2); vR += __shfl_xor(vR, 4);
    vI += __shfl_xor(vI, 1); vI += __shfl_xor(vI, 2); vI += __shfl_xor(vI, 4);
    const float invR = 1.f / sqrtf(vR * (1.f / 64.f) + 1e-6f);
    const float invI = 1.f / sqrtf(vI * (1.f / 64.f) + 1e-6f);
    float* orow = P.out + bb * RSTRIDE;
    float oR[8], oI[8];
    #pragma unroll
    for (int x = 0; x < 8; ++x) {
      const int d = d0 + x;
      oR[x] = (nr[x] - mR) * invR * P.ln_gr[d] + P.ln_br[d];
      oI[x] = (ni[x] - mI) * invI * P.ln_gi[d] + P.ln_bi[d];
    }
    *(float4*)&orow[640 + s * 64 + d0]      = make_float4(oR[0], oR[1], oR[2], oR[3]);
    *(float4*)&orow[640 + s * 64 + d0 + 4]  = make_float4(oR[4], oR[5], oR[6], oR[7]);
    *(float4*)&orow[2688 + s * 64 + d0]     = make_float4(oI[0], oI[1], oI[2], oI[3]);
    *(float4*)&orow[2688 + s * 64 + d0 + 4] = make_float4(oI[4], oI[5], oI[6], oI[7]);
  }
  __syncthreads();
  if (t < 64) {
    const int kk = t >> 3, xx = t & 7;
    float rv = s_rr[0][kk][xx] + s_rr[1][kk][xx] + s_rr[2][kk][xx] + s_rr[3][kk][xx];
    float iv = s_ri[0][kk][xx] + s_ri[1][kk][xx] + s_ri[2][kk][xx] + s_ri[3][kk][xx];
    float* orow = P.out + bb * RSTRIDE;
    orow[256 + t] = rv;
    orow[320 + t] = iv;
  }
}

__global__ __launch_bounds__(256) void finalize_k(const int* hist, const float* rowent,
                                                  float* out) {
  const int t = threadIdx.x;
  __shared__ float red[256];
  float se = 0.f;
  for (int i = t; i < 8192; i += 256) se += rowent[i];
  red[t] = se;
  __syncthreads();
  for (int off = 128; off >= 1; off >>= 1) {
    if (t < off) red[t] += red[t + off];
    __syncthreads();
  }
  if (t == 0) out[OFF_SENT] = red[0] / 8192.0f;
  __syncthreads();
  float ne = 0.f;
  if (t < 128) {
    const float pp = (float)hist[t] / 8192.0f;
    ne = -(pp * logf(pp + 1e-10f));
  }
  red[t] = ne;
  __syncthreads();
  for (int off = 128; off >= 1; off >>= 1) {
    if (t < off) red[t] += red[t + off];
    __syncthreads();
  }
  if (t == 0) out[OFF_NENT] = red[0] / logf(128.0f);
}

extern "C" void kernel_launch(void* const* d_in, const int* in_sizes, int n_in,
                              void* d_out, int out_size, void* d_ws, size_t ws_size,
                              hipStream_t stream) {
  (void)in_sizes; (void)n_in; (void)out_size; (void)ws_size;
  Params P;
  P.curr_r   = (const float*)d_in[0];
  P.curr_i   = (const float*)d_in[1];
  P.mem_r    = (const float*)d_in[2];
  P.mem_i    = (const float*)d_in[3];
  P.codebook = (const float*)d_in[4];
  P.qkv_Wr   = (const float*)d_in[5];
  P.qkv_Wi   = (const float*)d_in[6];
  P.qkv_br   = (const float*)d_in[7];
  P.qkv_bi   = (const float*)d_in[8];
  P.quad_Wr  = (const float*)d_in[9];
  P.quad_Wi  = (const float*)d_in[10];
  P.quad_br  = (const float*)d_in[11];
  P.quad_bi  = (const float*)d_in[12];
  P.sens_Wr  = (const float*)d_in[13];
  P.sens_Wi  = (const float*)d_in[14];
  P.sens_br  = (const float*)d_in[15];
  P.sens_bi  = (const float*)d_in[16];
  P.vis_pal  = (const float*)d_in[17];
  P.aud_pal  = (const float*)d_in[18];
  P.gate_W   = (const float*)d_in[19];
  P.gate_b   = (const float*)d_in[20];
  P.addr_W   = (const float*)d_in[21];
  P.addr_b   = (const float*)d_in[22];
  P.ln_gr    = (const float*)d_in[23];
  P.ln_br    = (const float*)d_in[24];
  P.ln_gi    = (const float*)d_in[25];
  P.ln_bi    = (const float*)d_in[26];
  P.out = (float*)d_out;
  P.hist = (int*)d_ws;
  P.rowent = (float*)((char*)d_ws + 512);

  hipMemsetAsync(d_ws, 0, 512, stream);
  mem_kernel<<<dim3(8192), dim3(256), 0, stream>>>(P);
  vq_kernel<<<dim3(NBLOCKS), dim3(256), 0, stream>>>(P);
  lin_kernel<<<dim3(NBLOCKS), dim3(256), 0, stream>>>(P);
  finalize_k<<<dim3(1), dim3(256), 0, stream>>>(P.hist, P.rowent, (float*)d_out);
}

// Round 12
// 252.337 us; speedup vs baseline: 3.7584x; 1.0577x over previous
//
#include <hip/hip_runtime.h>
#include <hip/hip_bf16.h>

// SACRSN_v84 — v12: merge clinears/gate/palettes into the per-row kernel
// (8192 blocks, weights read from L2 per row — overlaps HBM mem stream).
// vq_kernel (1024 blk) and finalize unchanged from passing R11.

#define NROWS 8
#define NBLOCKS 1024
#define RSTRIDE 4736

static constexpr size_t OFF_VQLOSS = 38797312UL;  // 8192*4736
static constexpr size_t OFF_IDX    = 38805504UL;
static constexpr size_t OFF_SENT   = 38813696UL;
static constexpr size_t OFF_NENT   = 38813697UL;

struct Params {
  const float* curr_r; const float* curr_i;
  const float* mem_r;  const float* mem_i;
  const float* codebook;
  const float* qkv_Wr; const float* qkv_Wi; const float* qkv_br; const float* qkv_bi;
  const float* quad_Wr; const float* quad_Wi; const float* quad_br; const float* quad_bi;
  const float* sens_Wr; const float* sens_Wi; const float* sens_br; const float* sens_bi;
  const float* vis_pal; const float* aud_pal;
  const float* gate_W; const float* gate_b;
  const float* addr_W; const float* addr_b;
  const float* ln_gr; const float* ln_br; const float* ln_gi; const float* ln_bi;
  float* out;
  int* hist;          // ws: 128 ints
  float* rowent;      // ws + 512 B: 8192 floats
};

// ================= row_main: everything except VQ, one row per block =================
__global__ __launch_bounds__(256) void row_main(Params P) {
  const int b = blockIdx.x;
  const int t = threadIdx.x;
  const int lane = t & 63;
  const int wv = t >> 6;

  __shared__ float zr[64], zi[64];
  __shared__ float s_qr[64], s_qi[64], s_kr[64], s_ki[64], s_vr[64], s_vi[64];
  __shared__ float sfl[128];
  __shared__ float s_sp[4][4][64];
  __shared__ float lp[4][32];
  __shared__ float s_eff[32];
  __shared__ float s_sim[32], s_attn[32];
  __shared__ float s_rr[4][8][8], s_ri[4][8][8];
  __shared__ float s_pv[4][32], s_pa[4][32];
  __shared__ float s_pvp[32], s_pap[32];
  __shared__ float s_vo[128], s_ao[128];
  __shared__ float s_wg, s_gate;

  // ---- A: issue mem loads (consumed much later) + stage z ----
  const size_t bb = (size_t)b;
  const int s = t >> 3, k = t & 7, d0 = k * 8;
  const float* mrp = P.mem_r + ((bb * 32 + s) * 64 + d0);
  const float* mip = P.mem_i + ((bb * 32 + s) * 64 + d0);
  float4 a0 = *(const float4*)mrp, a1 = *(const float4*)(mrp + 4);
  float4 b0 = *(const float4*)mip, b1 = *(const float4*)(mip + 4);
  float mr[8] = {a0.x, a0.y, a0.z, a0.w, a1.x, a1.y, a1.z, a1.w};
  float mi[8] = {b0.x, b0.y, b0.z, b0.w, b1.x, b1.y, b1.z, b1.w};

  if (t < 64)       zr[t]      = P.curr_r[bb * 64 + t];
  else if (t < 128) zi[t - 64] = P.curr_i[bb * 64 + (t - 64)];
  __syncthreads();

  float* orow = P.out + bb * RSTRIDE;

  // ---- B: clinears q,k,v,quad (wave cl = wv, full depth) + sens partials ----
  {
    const int j = lane, cl = wv;
    const float *Wr, *Wi, *br_, *bi_;
    if      (cl == 0) { Wr = P.qkv_Wr;        Wi = P.qkv_Wi;        br_ = P.qkv_br;       bi_ = P.qkv_bi;       }
    else if (cl == 1) { Wr = P.qkv_Wr + 4096; Wi = P.qkv_Wi + 4096; br_ = P.qkv_br + 64;  bi_ = P.qkv_bi + 64;  }
    else if (cl == 2) { Wr = P.qkv_Wr + 8192; Wi = P.qkv_Wi + 8192; br_ = P.qkv_br + 128; bi_ = P.qkv_bi + 128; }
    else              { Wr = P.quad_Wr;       Wi = P.quad_Wi;       br_ = P.quad_br;      bi_ = P.quad_bi;      }
    float aRR = 0.f, aRI = 0.f, aIR = 0.f, aII = 0.f;
    for (int d = 0; d < 64; ++d) {
      const float xr = zr[d], xi = zi[d];
      const float wr = Wr[d * 64 + j], wi = Wi[d * 64 + j];
      aRR += xr * wr; aRI += xr * wi; aIR += xi * wr; aII += xi * wi;
    }
    const float oR = (aRR + br_[j]) - (aII + bi_[j]);
    const float oI = (aRI + bi_[j]) + (aIR + br_[j]);
    if      (cl == 0) { s_qr[j] = oR; s_qi[j] = oI; }
    else if (cl == 1) { s_kr[j] = oR; s_ki[j] = oI; }
    else if (cl == 2) { s_vr[j] = oR; s_vi[j] = oI; }
    else              { orow[512 + j] = -oI; orow[576 + j] = oR; }  // q_r=-zi, q_i=zr
    // sens split-K partials (quarter qd = wv)
    float bRR = 0.f, bRI = 0.f, bIR = 0.f, bII = 0.f;
    for (int dd = 0; dd < 16; ++dd) {
      const int d = wv * 16 + dd;
      const float xr = zr[d], xi = zi[d];
      const float wr = P.sens_Wr[d * 64 + j], wi = P.sens_Wi[d * 64 + j];
      bRR += xr * wr; bRI += xr * wi; bIR += xi * wr; bII += xi * wi;
    }
    s_sp[wv][0][j] = bRR; s_sp[wv][1][j] = bRI; s_sp[wv][2][j] = bIR; s_sp[wv][3][j] = bII;
  }
  __syncthreads();

  // ---- C: sim partials (all) + addr partials (t<128) + wgate (w2) + gate (w3) ----
  {
    float sp = 0.f;
    #pragma unroll
    for (int x = 0; x < 8; ++x) sp += mr[x] * zr[d0 + x] + mi[x] * zi[d0 + x];
    sp += __shfl_xor(sp, 1); sp += __shfl_xor(sp, 2); sp += __shfl_xor(sp, 4);
    if (k == 0) s_sim[s] = sp;
  }
  if (t < 128) {
    const int q = t >> 5, l = t & 31;
    const float* zz = (q < 2) ? zr : zi;
    const int zb = (q & 1) * 32;
    float a = 0.f;
    for (int i = 0; i < 32; ++i) a += zz[zb + i] * P.addr_W[(q * 32 + i) * 32 + l];
    lp[q][l] = a;
  } else if (t < 192) {
    const int j = t - 128;
    float tw = zr[j] * P.gate_W[j] + zi[j] * P.gate_W[64 + j];
    #pragma unroll
    for (int m = 1; m <= 32; m <<= 1) tw += __shfl_xor(tw, m);
    if (j == 0) s_wg = tw;
  } else {
    const int j = t - 192;
    float g = s_qr[j] * s_kr[j] + s_qi[j] * s_ki[j];
    #pragma unroll
    for (int m = 1; m <= 32; m <<= 1) g += __shfl_xor(g, m);
    if (j == 0) s_gate = 1.f / (1.f + expf(-g));
  }
  __syncthreads();

  // ---- D: sim softmax (w0) | addr softmax/top3/eff (w1) | sens combine (w2) ----
  if (t < 32) {
    float v = s_sim[t];
    float mx = v;
    #pragma unroll
    for (int m = 16; m >= 1; m >>= 1) mx = fmaxf(mx, __shfl_xor(mx, m));
    float e = expf(v - mx);
    float sm = e;
    #pragma unroll
    for (int m = 16; m >= 1; m >>= 1) sm += __shfl_xor(sm, m);
    s_attn[t] = e / sm;
  } else if (t >= 64 && t < 96) {
    const int l = t - 64;
    float lg = lp[0][l] + lp[1][l] + lp[2][l] + lp[3][l] + P.addr_b[l];
    float mx = lg;
    #pragma unroll
    for (int m = 16; m >= 1; m >>= 1) mx = fmaxf(mx, __shfl_xor(mx, m));
    float e = expf(lg - mx);
    float sm = e;
    #pragma unroll
    for (int m = 16; m >= 1; m >>= 1) sm += __shfl_xor(sm, m);
    const float w = e / sm;
    float es = -(w * logf(w + 1e-10f));
    #pragma unroll
    for (int m = 16; m >= 1; m >>= 1) es += __shfl_xor(es, m);
    if (l == 0) P.rowent[b] = es;
    // top-3 (lax.top_k: ties -> lower index)
    const float myw = w;
    bool picked = false;
    float val = w; int idx = l;
    float sumtop = 0.f;
    #pragma unroll
    for (int it = 0; it < 3; ++it) {
      float v2 = val; int i2 = idx;
      #pragma unroll
      for (int m = 16; m >= 1; m >>= 1) {
        float ov = __shfl_xor(v2, m); int oi = __shfl_xor(i2, m);
        if (ov > v2 || (ov == v2 && oi < i2)) { v2 = ov; i2 = oi; }
      }
      sumtop += v2;
      if (l == i2) { picked = true; val = -1e30f; }
    }
    const float wgate = 1.f / (1.f + expf(-(s_wg + P.gate_b[0])));
    s_eff[l] = picked ? wgate * (myw / (sumtop + 1e-6f)) : 0.f;
  } else if (t >= 128 && t < 192) {
    const int j = t - 128;
    const float aRR = s_sp[0][0][j] + s_sp[1][0][j] + s_sp[2][0][j] + s_sp[3][0][j];
    const float aRI = s_sp[0][1][j] + s_sp[1][1][j] + s_sp[2][1][j] + s_sp[3][1][j];
    const float aIR = s_sp[0][2][j] + s_sp[1][2][j] + s_sp[2][2][j] + s_sp[3][2][j];
    const float aII = s_sp[0][3][j] + s_sp[1][3][j] + s_sp[2][3][j] + s_sp[3][3][j];
    const float oR = (aRR + P.sens_br[j]) - (aII + P.sens_bi[j]);
    const float oI = (aRI + P.sens_bi[j]) + (aIR + P.sens_br[j]);
    sfl[j] = oR; sfl[64 + j] = oI;
  }
  __syncthreads();

  // ---- E: read reduce partials + tanh/LN + stores + palette partials ----
  const float aw = s_attn[s];
  {
    float pr[8], pi[8];
    #pragma unroll
    for (int x = 0; x < 8; ++x) { pr[x] = aw * mr[x]; pi[x] = aw * mi[x]; }
    #pragma unroll
    for (int m = 8; m <= 32; m <<= 1) {
      #pragma unroll
      for (int x = 0; x < 8; ++x) { pr[x] += __shfl_xor(pr[x], m); pi[x] += __shfl_xor(pi[x], m); }
    }
    if (lane < 8) {
      #pragma unroll
      for (int x = 0; x < 8; ++x) { s_rr[wv][lane][x] = pr[x]; s_ri[wv][lane][x] = pi[x]; }
    }
  }
  {
    const float eff = s_eff[s];
    float nr[8], ni[8];
    #pragma unroll
    for (int x = 0; x < 8; ++x) {
      nr[x] = tanhf(mr[x] + eff * (zr[d0 + x] - mr[x]));
      ni[x] = tanhf(mi[x] + eff * (zi[d0 + x] - mi[x]));
    }
    float sR = 0.f, sI = 0.f;
    #pragma unroll
    for (int x = 0; x < 8; ++x) { sR += nr[x]; sI += ni[x]; }
    sR += __shfl_xor(sR, 1); sR += __shfl_xor(sR, 2); sR += __shfl_xor(sR, 4);
    sI += __shfl_xor(sI, 1); sI += __shfl_xor(sI, 2); sI += __shfl_xor(sI, 4);
    const float mR = sR * (1.f / 64.f), mI = sI * (1.f / 64.f);
    float vR = 0.f, vI = 0.f;
    #pragma unroll
    for (int x = 0; x < 8; ++x) {
      float dr = nr[x] - mR; vR += dr * dr;
      float di = ni[x] - mI; vI += di * di;
    }
    vR += __shfl_xor(vR, 1); vR += __shfl_xor(vR, 2); vR += __shfl_xor(vR, 4);
    vI += __shfl_xor(vI, 1); vI += __shfl_xor(vI, 2); vI += __shfl_xor(vI, 4);
    const float invR = 1.f / sqrtf(vR * (1.f / 64.f) + 1e-6f);
    const float invI = 1.f / sqrtf(vI * (1.f / 64.f) + 1e-6f);
    float oR[8], oI[8];
    #pragma unroll
    for (int x = 0; x < 8; ++x) {
      const int d = d0 + x;
      oR[x] = (nr[x] - mR) * invR * P.ln_gr[d] + P.ln_br[d];
      oI[x] = (ni[x] - mI) * invI * P.ln_gi[d] + P.ln_bi[d];
    }
    *(float4*)&orow[640 + s * 64 + d0]      = make_float4(oR[0], oR[1], oR[2], oR[3]);
    *(float4*)&orow[640 + s * 64 + d0 + 4]  = make_float4(oR[4], oR[5], oR[6], oR[7]);
    *(float4*)&orow[2688 + s * 64 + d0]     = make_float4(oI[0], oI[1], oI[2], oI[3]);
    *(float4*)&orow[2688 + s * 64 + d0 + 4] = make_float4(oI[4], oI[5], oI[6], oI[7]);
  }
  // palette score partials (sfl ready since D-barrier)
  if (t < 128) {
    const int a = t & 31, q = t >> 5;
    float sc = 0.f;
    for (int x = q * 32; x < q * 32 + 32; ++x) sc += sfl[x] * P.vis_pal[a * 128 + x];
    s_pv[q][a] = sc;
  } else {
    const int tt = t - 128, a = tt & 31, q = tt >> 5;
    float sc = 0.f;
    for (int x = q * 32; x < q * 32 + 32; ++x) sc += sfl[x] * P.aud_pal[a * 128 + x];
    s_pa[q][a] = sc;
  }
  __syncthreads();

  // ---- F: read combine (t<64) | vis softmax (w2 lanes 0-31) | aud softmax (w3 lanes 0-31) ----
  if (t < 64) {
    const int kk = t >> 3, xx = t & 7;
    float rv = s_rr[0][kk][xx] + s_rr[1][kk][xx] + s_rr[2][kk][xx] + s_rr[3][kk][xx];
    float iv = s_ri[0][kk][xx] + s_ri[1][kk][xx] + s_ri[2][kk][xx] + s_ri[3][kk][xx];
    orow[256 + t] = rv;
    orow[320 + t] = iv;
  } else if (t >= 128 && t < 160) {
    const int a = t - 128;
    float sc = s_pv[0][a] + s_pv[1][a] + s_pv[2][a] + s_pv[3][a];
    float mx = sc;
    #pragma unroll
    for (int m = 16; m >= 1; m >>= 1) mx = fmaxf(mx, __shfl_xor(mx, m));
    float e = expf(sc - mx);
    float sm = e;
    #pragma unroll
    for (int m = 16; m >= 1; m >>= 1) sm += __shfl_xor(sm, m);
    s_pvp[a] = e / sm;
  } else if (t >= 192 && t < 224) {
    const int a = t - 192;
    float sc = s_pa[0][a] + s_pa[1][a] + s_pa[2][a] + s_pa[3][a];
    float mx = sc;
    #pragma unroll
    for (int m = 16; m >= 1; m >>= 1) mx = fmaxf(mx, __shfl_xor(mx, m));
    float e = expf(sc - mx);
    float sm = e;
    #pragma unroll
    for (int m = 16; m >= 1; m >>= 1) sm += __shfl_xor(sm, m);
    s_pap[a] = e / sm;
  }
  __syncthreads();

  // ---- G: palette attend-out + g_r/g_i writes ----
  if (t < 128) {
    float v = 0.f;
    for (int a = 0; a < 32; ++a) v += s_pvp[a] * P.vis_pal[a * 128 + t];
    s_vo[t] = v;
  } else {
    const int j = t - 128;
    float v = 0.f;
    for (int a = 0; a < 32; ++a) v += s_pap[a] * P.aud_pal[a * 128 + j];
    s_ao[j] = v;
  }
  if (t < 64)       orow[128 + t] = s_vr[t] * s_gate;
  else if (t < 128) orow[192 + (t - 64)] = s_vi[t - 64] * s_gate;
  __syncthreads();

  // ---- H: exp_r / exp_i ----
  if (t < 64)       orow[384 + t] = s_vo[t] - s_ao[64 + t];            // exp_r
  else if (t < 128) orow[448 + (t - 64)] = s_vo[t] + s_ao[t - 64];     // exp_i
}

// ================= vq_kernel: unchanged from passing R11 =================
__global__ __launch_bounds__(256) void vq_kernel(Params P) {
  const int t = threadIdx.x;
  const int bid = blockIdx.x;
  const int lane = t & 63;
  const int wv = t >> 6;

  __shared__ __align__(16) float s_zr[NROWS][64], s_zi[NROWS][64];
  __shared__ double s_cbn[128];
  __shared__ double s_dall[NROWS][256];
  __shared__ float s_vqls[NROWS];
  __shared__ int s_idx[NROWS];

  {
    const float* cr = P.curr_r + (size_t)bid * (NROWS * 64);
    const float* ci = P.curr_i + (size_t)bid * (NROWS * 64);
    float* zr = &s_zr[0][0];
    float* zi = &s_zi[0][0];
    for (int i = t; i < NROWS * 64; i += 256) { zr[i] = cr[i]; zi[i] = ci[i]; }
  }
  {
    const float* cb = P.codebook + (t & 127) * 128 + (t >> 7) * 64;
    double a = 0.0;
    for (int d = 0; d < 64; ++d) { double w = (double)cb[d]; a = fma(w, w, a); }
    s_dall[0][t] = a;
    __syncthreads();
    if (t < 128) s_cbn[t] = s_dall[0][t] + s_dall[0][t + 128];
    __syncthreads();
  }
  {
    const int c = t & 127, h = t >> 7;
    const float* cb = P.codebook + c * 128 + h * 64;
    const float (*zb)[64] = h ? s_zi : s_zr;
    double acc[NROWS];
    #pragma unroll
    for (int r = 0; r < NROWS; ++r) acc[r] = 0.0;
    for (int d = 0; d < 64; ++d) {
      const double w = (double)cb[d];
      #pragma unroll
      for (int r = 0; r < NROWS; ++r) acc[r] = fma(w, (double)zb[r][d], acc[r]);
    }
    #pragma unroll
    for (int r = 0; r < NROWS; ++r) s_dall[r][h * 128 + c] = acc[r];
    __syncthreads();
    #pragma unroll
    for (int rr = 0; rr < 2; ++rr) {
      const int r = wv * 2 + rr;
      const double d0 = s_cbn[lane]      - 2.0 * (s_dall[r][lane]      + s_dall[r][128 + lane]);
      const double d1 = s_cbn[lane + 64] - 2.0 * (s_dall[r][64 + lane] + s_dall[r][192 + lane]);
      double sv = d0; int si = lane;
      if (d1 < sv) { sv = d1; si = lane + 64; }
      #pragma unroll
      for (int m = 1; m <= 32; m <<= 1) {
        double ov = __shfl_xor(sv, m);
        int oi = __shfl_xor(si, m);
        if (ov < sv || (ov == sv && oi < si)) { sv = ov; si = oi; }
      }
      if (lane == 0) { s_idx[r] = si; atomicAdd(&P.hist[si], 1); }
    }
    __syncthreads();
  }
  {
    #pragma unroll
    for (int rr = 0; rr < 2; ++rr) {
      const int r = wv * 2 + rr;
      const float* cb = P.codebook + (size_t)s_idx[r] * 128;
      float d0_ = cb[lane] - s_zr[r][lane];
      float d1_ = cb[64 + lane] - s_zi[r][lane];
      float v = d0_ * d0_ + d1_ * d1_;
      #pragma unroll
      for (int m = 1; m <= 32; m <<= 1) v += __shfl_xor(v, m);
      if (lane == 0) s_vqls[r] = 0.25f * v * (1.0f / 128.0f);
    }
  }
  __syncthreads();
  {
    const int j = t & 63, g = t >> 6;
    #pragma unroll
    for (int rr = 0; rr < 4; ++rr) {
      const int r = (g >> 1) * 4 + rr;
      float* orow = P.out + ((size_t)bid * NROWS + r) * RSTRIDE;
      const float* cb = P.codebook + (size_t)s_idx[r] * 128;
      if ((g & 1) == 0) {
        float z = s_zr[r][j];
        orow[j] = z + (cb[j] - z);
      } else {
        float z = s_zi[r][j];
        orow[64 + j] = z + (cb[64 + j] - z);
      }
    }
  }
  if (t < NROWS) {
    P.out[OFF_VQLOSS + (size_t)bid * NROWS + t] = s_vqls[t];
    P.out[OFF_IDX + (size_t)bid * NROWS + t] = (float)s_idx[t];
  }
}

__global__ __launch_bounds__(256) void finalize_k(const int* hist, const float* rowent,
                                                  float* out) {
  const int t = threadIdx.x;
  __shared__ float red[256];
  float se = 0.f;
  for (int i = t; i < 8192; i += 256) se += rowent[i];
  red[t] = se;
  __syncthreads();
  for (int off = 128; off >= 1; off >>= 1) {
    if (t < off) red[t] += red[t + off];
    __syncthreads();
  }
  if (t == 0) out[OFF_SENT] = red[0] / 8192.0f;
  __syncthreads();
  float ne = 0.f;
  if (t < 128) {
    const float pp = (float)hist[t] / 8192.0f;
    ne = -(pp * logf(pp + 1e-10f));
  }
  red[t] = ne;
  __syncthreads();
  for (int off = 128; off >= 1; off >>= 1) {
    if (t < off) red[t] += red[t + off];
    __syncthreads();
  }
  if (t == 0) out[OFF_NENT] = red[0] / logf(128.0f);
}

extern "C" void kernel_launch(void* const* d_in, const int* in_sizes, int n_in,
                              void* d_out, int out_size, void* d_ws, size_t ws_size,
                              hipStream_t stream) {
  (void)in_sizes; (void)n_in; (void)out_size; (void)ws_size;
  Params P;
  P.curr_r   = (const float*)d_in[0];
  P.curr_i   = (const float*)d_in[1];
  P.mem_r    = (const float*)d_in[2];
  P.mem_i    = (const float*)d_in[3];
  P.codebook = (const float*)d_in[4];
  P.qkv_Wr   = (const float*)d_in[5];
  P.qkv_Wi   = (const float*)d_in[6];
  P.qkv_br   = (const float*)d_in[7];
  P.qkv_bi   = (const float*)d_in[8];
  P.quad_Wr  = (const float*)d_in[9];
  P.quad_Wi  = (const float*)d_in[10];
  P.quad_br  = (const float*)d_in[11];
  P.quad_bi  = (const float*)d_in[12];
  P.sens_Wr  = (const float*)d_in[13];
  P.sens_Wi  = (const float*)d_in[14];
  P.sens_br  = (const float*)d_in[15];
  P.sens_bi  = (const float*)d_in[16];
  P.vis_pal  = (const float*)d_in[17];
  P.aud_pal  = (const float*)d_in[18];
  P.gate_W   = (const float*)d_in[19];
  P.gate_b   = (const float*)d_in[20];
  P.addr_W   = (const float*)d_in[21];
  P.addr_b   = (const float*)d_in[22];
  P.ln_gr    = (const float*)d_in[23];
  P.ln_br    = (const float*)d_in[24];
  P.ln_gi    = (const float*)d_in[25];
  P.ln_bi    = (const float*)d_in[26];
  P.out = (float*)d_out;
  P.hist = (int*)d_ws;
  P.rowent = (float*)((char*)d_ws + 512);

  hipMemsetAsync(d_ws, 0, 512, stream);
  row_main<<<dim3(8192), dim3(256), 0, stream>>>(P);
  vq_kernel<<<dim3(NBLOCKS), dim3(256), 0, stream>>>(P);
  finalize_k<<<dim3(1), dim3(256), 0, stream>>>(P.hist, P.rowent, (float*)d_out);
}